// Round 4
// baseline (566.643 us; speedup 1.0000x reference)
//
#include <hip/hip_runtime.h>

// GAT node regressor: 3 GAT layers (HID=64, 4 heads x 16) + linear head.
// CSR-by-dst built once per call via bucketed counting sort (no random global
// scatter). Per layer:
//   k_gemm: xh = h@W (LDS-tiled fp32) fused with al_s/al_d head reductions
//   k_agg : wave-per-dst-node gather, single pass (m fixed at e_self per head).
//           Logit phase: lane=edge computes all 4 heads' pe -> LDS (padded).
//           Accumulate phase: lane=(edge-in-group, col-quad); one
//           global_load_dwordx4 covers 4 edges per instr; per-lane float4
//           partials merged with shfl_xor(16,32). Layer 2 fuses h@out_w.

#define NBMAX 512   // max dst buckets (dst>>8); N=100K -> 391
#define SCHUNK 4096 // edges per k_bscatter block
#define BCAP 8192   // per-bucket LDS src capacity in k_bfinal (avg 4096)

__global__ __launch_bounds__(256) void k_zero(int* p, int n) {
    int i = blockIdx.x * 256 + threadIdx.x;
    if (i < n) p[i] = 0;
}

__global__ __launch_bounds__(256) void k_bhist(const int* __restrict__ dst, int* __restrict__ bhist, int e) {
    __shared__ unsigned int h[NBMAX];
    int t = threadIdx.x;
    h[t] = 0;
    h[t + 256] = 0;
    __syncthreads();
    for (int i = blockIdx.x * 256 + t; i < e; i += gridDim.x * 256)
        atomicAdd(&h[dst[i] >> 8], 1u);
    __syncthreads();
    if (h[t]) atomicAdd(&bhist[t], (int)h[t]);
    if (h[t + 256]) atomicAdd(&bhist[t + 256], (int)h[t + 256]);
}

__global__ __launch_bounds__(512) void k_bscan(const int* __restrict__ bhist, int* __restrict__ boffs,
                                               int* __restrict__ bfill, int nb, int e) {
    __shared__ int s[NBMAX];
    int t = threadIdx.x;
    int v = (t < nb) ? bhist[t] : 0;
    s[t] = v;
    __syncthreads();
    for (int o = 1; o < 512; o <<= 1) {
        int add = (t >= o) ? s[t - o] : 0;
        __syncthreads();
        s[t] += add;
        __syncthreads();
    }
    boffs[t] = s[t] - v;  // exclusive
    if (t == 511) boffs[512] = s[511];
    bfill[t] = 0;
}

// Block-local counting sort of a 4096-edge chunk by dst>>8, then streamed
// writes of sorted runs. Packs src (17b) | (dst&255)<<24 into 4B.
__global__ __launch_bounds__(512) void k_bscatter(const int* __restrict__ src, const int* __restrict__ dst,
                                                  const int* __restrict__ boffs, int* __restrict__ bfill,
                                                  unsigned int* __restrict__ edata, int e) {
    __shared__ unsigned int hist[NBMAX];   // counts, then cursor
    __shared__ unsigned int loc[NBMAX];    // local exclusive offsets
    __shared__ int gbase[NBMAX];
    __shared__ unsigned int stmp[NBMAX];
    __shared__ unsigned int sortbuf[SCHUNK];
    __shared__ int posbuf[SCHUNK];
    int t = threadIdx.x;
    int i0 = blockIdx.x * SCHUNK;
    int cnt = min(SCHUNK, e - i0);
    hist[t] = 0;
    __syncthreads();
    for (int j = t; j < cnt; j += 512) atomicAdd(&hist[dst[i0 + j] >> 8], 1u);
    __syncthreads();
    unsigned int v = hist[t];
    stmp[t] = v;
    __syncthreads();
    for (int o = 1; o < 512; o <<= 1) {
        unsigned int add = (t >= o) ? stmp[t - o] : 0;
        __syncthreads();
        stmp[t] += add;
        __syncthreads();
    }
    loc[t] = stmp[t] - v;
    int gb = 0;
    if (v > 0) gb = atomicAdd(&bfill[t], (int)v);  // reserve contiguous run in bucket t
    gbase[t] = boffs[t] + gb - (int)loc[t];
    hist[t] = loc[t];  // cursor
    __syncthreads();
    for (int j = t; j < cnt; j += 512) {
        int d = dst[i0 + j];
        int s = src[i0 + j];
        int b = d >> 8;
        unsigned int p = atomicAdd(&hist[b], 1u);
        sortbuf[p] = (unsigned int)s | ((unsigned int)(d & 255) << 24);
        posbuf[p] = gbase[b] + (int)p;
    }
    __syncthreads();
    for (int j = t; j < cnt; j += 512) edata[posbuf[j]] = sortbuf[j];
}

// One block per bucket: 256-bin counting sort by local dst; coalesced output.
__global__ __launch_bounds__(256) void k_bfinal(const unsigned int* __restrict__ edata,
                                                const int* __restrict__ boffs, int* __restrict__ offs,
                                                int* __restrict__ ssrc, int n, int nb) {
    __shared__ unsigned int hist[256];
    __shared__ unsigned int stmp[256];
    __shared__ unsigned int loc[256];
    __shared__ unsigned int srcbuf[BCAP];
    int b = blockIdx.x;
    int t = threadIdx.x;
    int e0 = boffs[b], e1 = boffs[b + 1];
    int cnt = e1 - e0;
    hist[t] = 0;
    __syncthreads();
    for (int j = t; j < cnt; j += 256) atomicAdd(&hist[edata[e0 + j] >> 24], 1u);
    __syncthreads();
    unsigned int v = hist[t];
    stmp[t] = v;
    __syncthreads();
    for (int o = 1; o < 256; o <<= 1) {
        unsigned int add = (t >= o) ? stmp[t - o] : 0;
        __syncthreads();
        stmp[t] += add;
        __syncthreads();
    }
    loc[t] = stmp[t] - v;
    int node = b * 256 + t;
    if (node < n) offs[node] = e0 + (int)loc[t];
    if (b == nb - 1 && t == 0) offs[n] = e1;
    hist[t] = loc[t];  // cursor
    __syncthreads();
    if (cnt <= BCAP) {
        for (int j = t; j < cnt; j += 256) {
            unsigned int p = edata[e0 + j];
            unsigned int pos = atomicAdd(&hist[p >> 24], 1u);
            srcbuf[pos] = p & 0xFFFFFFu;
        }
        __syncthreads();
        for (int j = t; j < cnt; j += 256) ssrc[e0 + j] = (int)srcbuf[j];
    } else {  // safety fallback (never hit for Poisson(4096) buckets)
        for (int j = t; j < cnt; j += 256) {
            unsigned int p = edata[e0 + j];
            unsigned int pos = atomicAdd(&hist[p >> 24], 1u);
            ssrc[e0 + (int)pos] = (int)(p & 0xFFFFFFu);
        }
    }
}

// xh = h @ W  (h: [n, D_IN], W: [D_IN, 64]) fused with per-head attention logits.
template <int D_IN>
__global__ __launch_bounds__(256) void k_gemm(const float* __restrict__ h, const float* __restrict__ W,
                                              const float* __restrict__ asrc, const float* __restrict__ adst,
                                              float* __restrict__ xh, float* __restrict__ als,
                                              float* __restrict__ ald, int n) {
    constexpr int HSTR = D_IN + 4;
    __shared__ float hlds[64 * HSTR];
    int t = threadIdx.x;
    int node0 = blockIdx.x * 64;
    constexpr int HTOT = 64 * D_IN / 4;
    for (int i = t; i < HTOT; i += 256) {
        int f = i * 4;
        int nd = f / D_IN, k = f % D_IN;
        float4 val = make_float4(0.f, 0.f, 0.f, 0.f);
        if (node0 + nd < n) val = *(const float4*)(h + (size_t)(node0 + nd) * D_IN + k);
        *(float4*)(hlds + nd * HSTR + k) = val;
    }
    __syncthreads();
    int cg = t & 15, ng = t >> 4;
    float4 acc[4];
#pragma unroll
    for (int i = 0; i < 4; ++i) acc[i] = make_float4(0.f, 0.f, 0.f, 0.f);
    for (int k = 0; k < D_IN; k += 4) {
        float4 w0 = *(const float4*)(W + (size_t)(k + 0) * 64 + cg * 4);
        float4 w1 = *(const float4*)(W + (size_t)(k + 1) * 64 + cg * 4);
        float4 w2 = *(const float4*)(W + (size_t)(k + 2) * 64 + cg * 4);
        float4 w3 = *(const float4*)(W + (size_t)(k + 3) * 64 + cg * 4);
#pragma unroll
        for (int i = 0; i < 4; ++i) {
            float4 hv = *(const float4*)(hlds + (ng * 4 + i) * HSTR + k);
            acc[i].x += hv.x * w0.x + hv.y * w1.x + hv.z * w2.x + hv.w * w3.x;
            acc[i].y += hv.x * w0.y + hv.y * w1.y + hv.z * w2.y + hv.w * w3.y;
            acc[i].z += hv.x * w0.z + hv.y * w1.z + hv.z * w2.z + hv.w * w3.z;
            acc[i].w += hv.x * w0.w + hv.y * w1.w + hv.z * w2.w + hv.w * w3.w;
        }
    }
    float4 as4 = *(const float4*)(asrc + cg * 4);
    float4 ad4 = *(const float4*)(adst + cg * 4);
#pragma unroll
    for (int i = 0; i < 4; ++i) {
        int node = node0 + ng * 4 + i;
        float ps = acc[i].x * as4.x + acc[i].y * as4.y + acc[i].z * as4.z + acc[i].w * as4.w;
        float pd = acc[i].x * ad4.x + acc[i].y * ad4.y + acc[i].z * ad4.z + acc[i].w * ad4.w;
        ps += __shfl_xor(ps, 1, 64);
        ps += __shfl_xor(ps, 2, 64);
        pd += __shfl_xor(pd, 1, 64);
        pd += __shfl_xor(pd, 2, 64);
        if (node < n) {
            *(float4*)(xh + (size_t)node * 64 + cg * 4) = acc[i];
            if ((cg & 3) == 0) {
                als[node * 4 + (cg >> 2)] = ps;
                ald[node * 4 + (cg >> 2)] = pd;
            }
        }
    }
}

__device__ inline float4 lrelu4(float4 v) {
    float4 r;
    r.x = v.x >= 0.f ? v.x : 0.2f * v.x;
    r.y = v.y >= 0.f ? v.y : 0.2f * v.y;
    r.z = v.z >= 0.f ? v.z : 0.2f * v.z;
    r.w = v.w >= 0.f ? v.w : 0.2f * v.w;
    return r;
}

__device__ inline float pick4(float4 v, int h) {
    float r = v.x;
    r = (h == 1) ? v.y : r;
    r = (h == 2) ? v.z : r;
    r = (h == 3) ? v.w : r;
    return r;
}

// One wave per destination node. Single pass (m = e_self per head).
// Logit phase: lane = edge slot (64 edges/chunk), computes pe for all 4 heads,
// writes padded LDS (inactive lanes write u=v, pe=0).
// Accumulate phase: lane = (sub=lane>>4 edge-in-group, cq=lane&15 col-quad);
// one global_load_dwordx4 per lane covers 4 edges per wave instruction.
__global__ __launch_bounds__(256) void k_agg(const float* __restrict__ xh, const float* __restrict__ als,
                                             const float* __restrict__ ald, const int* __restrict__ offs,
                                             const int* __restrict__ ssrc, const float* __restrict__ bias,
                                             float* __restrict__ hout, const float* __restrict__ outw,
                                             const float* __restrict__ outb, float* __restrict__ fout, int n) {
    __shared__ int s_u[4][64];
    __shared__ float s_pe[4][64 * 4];
    int wslot = threadIdx.x >> 6;
    int lane = threadIdx.x & 63;
    int v = (blockIdx.x * 256 + threadIdx.x) >> 6;
    if (v >= n) return;
    int* ub = s_u[wslot];
    float* peb = s_pe[wslot];
    int sub = lane >> 4;   // edge-in-group (accumulate phase)
    int cq = lane & 15;    // column quad -> cols cq*4..cq*4+3
    int headq = cq >> 2;   // head of those columns

    int start = offs[v], end = offs[v + 1];
    float4 ald4 = *(const float4*)(ald + 4 * (size_t)v);
    float4 als4v = *(const float4*)(als + 4 * (size_t)v);
    float4 m4 = lrelu4(make_float4(als4v.x + ald4.x, als4v.y + ald4.y, als4v.z + ald4.z, als4v.w + ald4.w));

    float4 zp4 = make_float4(0.f, 0.f, 0.f, 0.f);
    // self term (pe_self = 1) only on sub==0 lanes (others would double-count)
    float4 acc = make_float4(0.f, 0.f, 0.f, 0.f);
    if (sub == 0) acc = *(const float4*)(xh + ((size_t)v << 6) + cq * 4);

    for (int s0 = start; s0 < end; s0 += 64) {
        int cnt = min(64, end - s0);
        bool act = lane < cnt;
        int u = v;
        float4 alu = make_float4(-1e30f, -1e30f, -1e30f, -1e30f);
        if (act) {
            u = ssrc[s0 + lane];
            alu = *(const float4*)(als + 4 * (size_t)u);
        }
        float4 e4 = lrelu4(make_float4(alu.x + ald4.x, alu.y + ald4.y, alu.z + ald4.z, alu.w + ald4.w));
        float4 pe;
        pe.x = __expf(e4.x - m4.x);  // inactive lanes -> exp(-huge) = 0
        pe.y = __expf(e4.y - m4.y);
        pe.z = __expf(e4.z - m4.z);
        pe.w = __expf(e4.w - m4.w);
        zp4.x += pe.x; zp4.y += pe.y; zp4.z += pe.z; zp4.w += pe.w;
        ub[lane] = u;                       // padded: all 64 lanes write
        *(float4*)(peb + lane * 4) = pe;    // same-wave LDS RAW, no barrier needed
        int ngroups = (cnt + 3) >> 2;
        int g = 0;
        for (; g + 2 <= ngroups; g += 2) {
            int e0 = g * 4 + sub, e1 = e0 + 4;
            int u0 = ub[e0], u1 = ub[e1];
            float p0 = peb[e0 * 4 + headq];
            float p1 = peb[e1 * 4 + headq];
            float4 x0 = *(const float4*)(xh + ((size_t)u0 << 6) + cq * 4);
            float4 x1 = *(const float4*)(xh + ((size_t)u1 << 6) + cq * 4);
            acc.x += p0 * x0.x; acc.y += p0 * x0.y; acc.z += p0 * x0.z; acc.w += p0 * x0.w;
            acc.x += p1 * x1.x; acc.y += p1 * x1.y; acc.z += p1 * x1.z; acc.w += p1 * x1.w;
        }
        for (; g < ngroups; ++g) {
            int e0 = g * 4 + sub;
            int u0 = ub[e0];
            float p0 = peb[e0 * 4 + headq];
            float4 x0 = *(const float4*)(xh + ((size_t)u0 << 6) + cq * 4);
            acc.x += p0 * x0.x; acc.y += p0 * x0.y; acc.z += p0 * x0.z; acc.w += p0 * x0.w;
        }
    }
    // merge the 4 sub-group partials: lanes ±16, ±32 hold same cq
    acc.x += __shfl_xor(acc.x, 16, 64); acc.y += __shfl_xor(acc.y, 16, 64);
    acc.z += __shfl_xor(acc.z, 16, 64); acc.w += __shfl_xor(acc.w, 16, 64);
    acc.x += __shfl_xor(acc.x, 32, 64); acc.y += __shfl_xor(acc.y, 32, 64);
    acc.z += __shfl_xor(acc.z, 32, 64); acc.w += __shfl_xor(acc.w, 32, 64);
    // z: full-wave reduction of per-lane partials (logit phase was lane=edge)
#pragma unroll
    for (int d = 1; d < 64; d <<= 1) {
        zp4.x += __shfl_xor(zp4.x, d, 64);
        zp4.y += __shfl_xor(zp4.y, d, 64);
        zp4.z += __shfl_xor(zp4.z, d, 64);
        zp4.w += __shfl_xor(zp4.w, d, 64);
    }
    float z = 1.f + pick4(zp4, headq);  // +1 = self edge
    float rz = 1.f / (z + 1e-16f);
    float4 b4 = *(const float4*)(bias + cq * 4);
    float4 o;
    o.x = fmaxf(acc.x * rz + b4.x, 0.f);
    o.y = fmaxf(acc.y * rz + b4.y, 0.f);
    o.z = fmaxf(acc.z * rz + b4.z, 0.f);
    o.w = fmaxf(acc.w * rz + b4.w, 0.f);
    if (outw) {
        float4 ow = *(const float4*)(outw + cq * 4);
        float t = o.x * ow.x + o.y * ow.y + o.z * ow.z + o.w * ow.w;
        t += __shfl_xor(t, 1, 64);
        t += __shfl_xor(t, 2, 64);
        t += __shfl_xor(t, 4, 64);
        t += __shfl_xor(t, 8, 64);  // sums the 16 col-quads within each sub-group
        if (lane == 0) fout[v] = t + outb[0];
    } else {
        if (sub == 0) *(float4*)(hout + ((size_t)v << 6) + cq * 4) = o;
    }
}

extern "C" void kernel_launch(void* const* d_in, const int* in_sizes, int n_in,
                              void* d_out, int out_size, void* d_ws, size_t ws_size,
                              hipStream_t stream) {
    const float* x = (const float*)d_in[0];
    const int* ei = (const int*)d_in[1];
    const float* w[3] = {(const float*)d_in[2], (const float*)d_in[6], (const float*)d_in[10]};
    const float* as[3] = {(const float*)d_in[3], (const float*)d_in[7], (const float*)d_in[11]};
    const float* ad[3] = {(const float*)d_in[4], (const float*)d_in[8], (const float*)d_in[12]};
    const float* b[3] = {(const float*)d_in[5], (const float*)d_in[9], (const float*)d_in[13]};
    const float* outw = (const float*)d_in[14];
    const float* outb = (const float*)d_in[15];

    const int N = in_sizes[0] / 128;
    const int E = in_sizes[1] / 2;
    const int* src = ei;
    const int* dst = ei + E;
    const int NB = (N + 255) / 256;  // 391 <= NBMAX

    char* ws = (char*)d_ws;
    auto alloc = [&](size_t bytes) -> void* {
        void* p = (void*)ws;
        ws += (bytes + 255) & ~(size_t)255;
        return p;
    };
    int* bhist = (int*)alloc(NBMAX * 4);
    int* boffs = (int*)alloc((NBMAX + 1) * 4);
    int* bfill = (int*)alloc(NBMAX * 4);
    int* offs = (int*)alloc((size_t)(N + 1) * 4);
    int* ssrc = (int*)alloc((size_t)E * 4);
    float* xh = (float*)alloc((size_t)N * 64 * 4);
    float* hbuf = (float*)alloc((size_t)N * 64 * 4);
    float* als = (float*)alloc((size_t)N * 4 * 4);
    float* ald = (float*)alloc((size_t)N * 4 * 4);
    // edata (E*4B) aliases xh (N*256B): dead before the first k_gemm writes xh.
    unsigned int* edata = (unsigned int*)xh;

    k_zero<<<(NBMAX + 255) / 256, 256, 0, stream>>>(bhist, NBMAX);
    k_bhist<<<256, 256, 0, stream>>>(dst, bhist, E);
    k_bscan<<<1, 512, 0, stream>>>(bhist, boffs, bfill, NB, E);
    k_bscatter<<<(E + SCHUNK - 1) / SCHUNK, 512, 0, stream>>>(src, dst, boffs, bfill, edata, E);
    k_bfinal<<<NB, 256, 0, stream>>>(edata, boffs, offs, ssrc, N, NB);

    const int gblocks = (N + 63) / 64;
    const int ablocks = (N + 3) / 4;

    k_gemm<128><<<gblocks, 256, 0, stream>>>(x, w[0], as[0], ad[0], xh, als, ald, N);
    k_agg<<<ablocks, 256, 0, stream>>>(xh, als, ald, offs, ssrc, b[0], hbuf, nullptr, nullptr, nullptr, N);
    k_gemm<64><<<gblocks, 256, 0, stream>>>(hbuf, w[1], as[1], ad[1], xh, als, ald, N);
    k_agg<<<ablocks, 256, 0, stream>>>(xh, als, ald, offs, ssrc, b[1], hbuf, nullptr, nullptr, nullptr, N);
    k_gemm<64><<<gblocks, 256, 0, stream>>>(hbuf, w[2], as[2], ad[2], xh, als, ald, N);
    k_agg<<<ablocks, 256, 0, stream>>>(xh, als, ald, offs, ssrc, b[2], nullptr, outw, outb, (float*)d_out, N);
}

// Round 5
// 562.842 us; speedup vs baseline: 1.0068x; 1.0068x over previous
//
#include <hip/hip_runtime.h>

// GAT node regressor: 3 GAT layers (HID=64, 4 heads x 16) + linear head.
// CSR-by-dst built once per call via bucketed counting sort. Per layer:
//   k_gemm: xh = h@W (LDS-tiled fp32) fused with al_s/al_d head reductions
//   k_edge: per-edge softmax numerators pe[j][h] (coalesced, edge-parallel)
//   k_agg : wave-per-dst-node gather (round-3 structure: lane=col, 64-edge
//           chunks staged in LDS, MLP-4 row-gather loop). Layer 2 fuses h@out_w.

#define NBMAX 512   // max dst buckets (dst>>8); N=100K -> 391
#define SCHUNK 4096 // edges per k_bscatter block
#define BCAP 8192   // per-bucket LDS src capacity in k_bfinal (avg 4096)

__global__ __launch_bounds__(256) void k_zero(int* p, int n) {
    int i = blockIdx.x * 256 + threadIdx.x;
    if (i < n) p[i] = 0;
}

__global__ __launch_bounds__(256) void k_bhist(const int* __restrict__ dst, int* __restrict__ bhist, int e) {
    __shared__ unsigned int h[NBMAX];
    int t = threadIdx.x;
    h[t] = 0;
    h[t + 256] = 0;
    __syncthreads();
    for (int i = blockIdx.x * 256 + t; i < e; i += gridDim.x * 256)
        atomicAdd(&h[dst[i] >> 8], 1u);
    __syncthreads();
    if (h[t]) atomicAdd(&bhist[t], (int)h[t]);
    if (h[t + 256]) atomicAdd(&bhist[t + 256], (int)h[t + 256]);
}

__global__ __launch_bounds__(512) void k_bscan(const int* __restrict__ bhist, int* __restrict__ boffs,
                                               int* __restrict__ bfill, int nb, int e) {
    __shared__ int s[NBMAX];
    int t = threadIdx.x;
    int v = (t < nb) ? bhist[t] : 0;
    s[t] = v;
    __syncthreads();
    for (int o = 1; o < 512; o <<= 1) {
        int add = (t >= o) ? s[t - o] : 0;
        __syncthreads();
        s[t] += add;
        __syncthreads();
    }
    boffs[t] = s[t] - v;  // exclusive
    if (t == 511) boffs[512] = s[511];
    bfill[t] = 0;
}

// Block-local counting sort of a 4096-edge chunk by dst>>8, then streamed
// writes of sorted runs. Packs src (17b) | (dst&255)<<24 into 4B.
__global__ __launch_bounds__(512) void k_bscatter(const int* __restrict__ src, const int* __restrict__ dst,
                                                  const int* __restrict__ boffs, int* __restrict__ bfill,
                                                  unsigned int* __restrict__ edata, int e) {
    __shared__ unsigned int hist[NBMAX];   // counts, then cursor
    __shared__ unsigned int loc[NBMAX];    // local exclusive offsets
    __shared__ int gbase[NBMAX];
    __shared__ unsigned int stmp[NBMAX];
    __shared__ unsigned int sortbuf[SCHUNK];
    __shared__ int posbuf[SCHUNK];
    int t = threadIdx.x;
    int i0 = blockIdx.x * SCHUNK;
    int cnt = min(SCHUNK, e - i0);
    hist[t] = 0;
    __syncthreads();
    for (int j = t; j < cnt; j += 512) atomicAdd(&hist[dst[i0 + j] >> 8], 1u);
    __syncthreads();
    unsigned int v = hist[t];
    stmp[t] = v;
    __syncthreads();
    for (int o = 1; o < 512; o <<= 1) {
        unsigned int add = (t >= o) ? stmp[t - o] : 0;
        __syncthreads();
        stmp[t] += add;
        __syncthreads();
    }
    loc[t] = stmp[t] - v;
    int gb = 0;
    if (v > 0) gb = atomicAdd(&bfill[t], (int)v);  // reserve contiguous run in bucket t
    gbase[t] = boffs[t] + gb - (int)loc[t];
    hist[t] = loc[t];  // cursor
    __syncthreads();
    for (int j = t; j < cnt; j += 512) {
        int d = dst[i0 + j];
        int s = src[i0 + j];
        int b = d >> 8;
        unsigned int p = atomicAdd(&hist[b], 1u);
        sortbuf[p] = (unsigned int)s | ((unsigned int)(d & 255) << 24);
        posbuf[p] = gbase[b] + (int)p;
    }
    __syncthreads();
    for (int j = t; j < cnt; j += 512) edata[posbuf[j]] = sortbuf[j];
}

// One block per bucket: 256-bin counting sort by local dst; coalesced output
// of offs, ssrc (sorted srcs) and sdst (sorted dsts, for k_edge).
__global__ __launch_bounds__(256) void k_bfinal(const unsigned int* __restrict__ edata,
                                                const int* __restrict__ boffs, int* __restrict__ offs,
                                                int* __restrict__ ssrc, int* __restrict__ sdst,
                                                int n, int nb) {
    __shared__ unsigned int hist[256];
    __shared__ unsigned int stmp[256];
    __shared__ unsigned int loc[256];
    __shared__ unsigned int srcbuf[BCAP];
    __shared__ unsigned char dstbuf[BCAP];
    int b = blockIdx.x;
    int t = threadIdx.x;
    int e0 = boffs[b], e1 = boffs[b + 1];
    int cnt = e1 - e0;
    hist[t] = 0;
    __syncthreads();
    for (int j = t; j < cnt; j += 256) atomicAdd(&hist[edata[e0 + j] >> 24], 1u);
    __syncthreads();
    unsigned int v = hist[t];
    stmp[t] = v;
    __syncthreads();
    for (int o = 1; o < 256; o <<= 1) {
        unsigned int add = (t >= o) ? stmp[t - o] : 0;
        __syncthreads();
        stmp[t] += add;
        __syncthreads();
    }
    loc[t] = stmp[t] - v;
    int node = b * 256 + t;
    if (node < n) offs[node] = e0 + (int)loc[t];
    if (b == nb - 1 && t == 0) offs[n] = e1;
    hist[t] = loc[t];  // cursor
    __syncthreads();
    if (cnt <= BCAP) {
        for (int j = t; j < cnt; j += 256) {
            unsigned int p = edata[e0 + j];
            unsigned int pos = atomicAdd(&hist[p >> 24], 1u);
            srcbuf[pos] = p & 0xFFFFFFu;
            dstbuf[pos] = (unsigned char)(p >> 24);
        }
        __syncthreads();
        for (int j = t; j < cnt; j += 256) {
            ssrc[e0 + j] = (int)srcbuf[j];
            sdst[e0 + j] = b * 256 + (int)dstbuf[j];
        }
    } else {  // safety fallback (never hit for Poisson(4096) buckets)
        for (int j = t; j < cnt; j += 256) {
            unsigned int p = edata[e0 + j];
            unsigned int pos = atomicAdd(&hist[p >> 24], 1u);
            ssrc[e0 + (int)pos] = (int)(p & 0xFFFFFFu);
            sdst[e0 + (int)pos] = b * 256 + (int)(p >> 24);
        }
    }
}

// xh = h @ W  (h: [n, D_IN], W: [D_IN, 64]) fused with per-head attention logits.
template <int D_IN>
__global__ __launch_bounds__(256) void k_gemm(const float* __restrict__ h, const float* __restrict__ W,
                                              const float* __restrict__ asrc, const float* __restrict__ adst,
                                              float* __restrict__ xh, float* __restrict__ als,
                                              float* __restrict__ ald, int n) {
    constexpr int HSTR = D_IN + 4;
    __shared__ float hlds[64 * HSTR];
    int t = threadIdx.x;
    int node0 = blockIdx.x * 64;
    constexpr int HTOT = 64 * D_IN / 4;
    for (int i = t; i < HTOT; i += 256) {
        int f = i * 4;
        int nd = f / D_IN, k = f % D_IN;
        float4 val = make_float4(0.f, 0.f, 0.f, 0.f);
        if (node0 + nd < n) val = *(const float4*)(h + (size_t)(node0 + nd) * D_IN + k);
        *(float4*)(hlds + nd * HSTR + k) = val;
    }
    __syncthreads();
    int cg = t & 15, ng = t >> 4;
    float4 acc[4];
#pragma unroll
    for (int i = 0; i < 4; ++i) acc[i] = make_float4(0.f, 0.f, 0.f, 0.f);
    for (int k = 0; k < D_IN; k += 4) {
        float4 w0 = *(const float4*)(W + (size_t)(k + 0) * 64 + cg * 4);
        float4 w1 = *(const float4*)(W + (size_t)(k + 1) * 64 + cg * 4);
        float4 w2 = *(const float4*)(W + (size_t)(k + 2) * 64 + cg * 4);
        float4 w3 = *(const float4*)(W + (size_t)(k + 3) * 64 + cg * 4);
#pragma unroll
        for (int i = 0; i < 4; ++i) {
            float4 hv = *(const float4*)(hlds + (ng * 4 + i) * HSTR + k);
            acc[i].x += hv.x * w0.x + hv.y * w1.x + hv.z * w2.x + hv.w * w3.x;
            acc[i].y += hv.x * w0.y + hv.y * w1.y + hv.z * w2.y + hv.w * w3.y;
            acc[i].z += hv.x * w0.z + hv.y * w1.z + hv.z * w2.z + hv.w * w3.z;
            acc[i].w += hv.x * w0.w + hv.y * w1.w + hv.z * w2.w + hv.w * w3.w;
        }
    }
    float4 as4 = *(const float4*)(asrc + cg * 4);
    float4 ad4 = *(const float4*)(adst + cg * 4);
#pragma unroll
    for (int i = 0; i < 4; ++i) {
        int node = node0 + ng * 4 + i;
        float ps = acc[i].x * as4.x + acc[i].y * as4.y + acc[i].z * as4.z + acc[i].w * as4.w;
        float pd = acc[i].x * ad4.x + acc[i].y * ad4.y + acc[i].z * ad4.z + acc[i].w * ad4.w;
        ps += __shfl_xor(ps, 1, 64);
        ps += __shfl_xor(ps, 2, 64);
        pd += __shfl_xor(pd, 1, 64);
        pd += __shfl_xor(pd, 2, 64);
        if (node < n) {
            *(float4*)(xh + (size_t)node * 64 + cg * 4) = acc[i];
            if ((cg & 3) == 0) {
                als[node * 4 + (cg >> 2)] = ps;
                ald[node * 4 + (cg >> 2)] = pd;
            }
        }
    }
}

__device__ inline float4 lrelu4(float4 v) {
    float4 r;
    r.x = v.x >= 0.f ? v.x : 0.2f * v.x;
    r.y = v.y >= 0.f ? v.y : 0.2f * v.y;
    r.z = v.z >= 0.f ? v.z : 0.2f * v.z;
    r.w = v.w >= 0.f ? v.w : 0.2f * v.w;
    return r;
}

__device__ inline float pick4(float4 v, int h) {
    float r = v.x;
    r = (h == 1) ? v.y : r;
    r = (h == 2) ? v.z : r;
    r = (h == 3) ? v.w : r;
    return r;
}

// Edge-parallel softmax numerators: pe[j][h] = exp(lrelu(als[u]+ald[d]) - m[d]),
// m[d] = lrelu(als[d]+ald[d]) (self-logit as the per-head shift; single-pass,
// algebraically identical to ref's max-subtraction). Coalesced float4 stores;
// sdst is sorted so ald[d]/als[d] loads hit L1 in runs.
__global__ __launch_bounds__(256) void k_edge(const int* __restrict__ ssrc, const int* __restrict__ sdst,
                                              const float* __restrict__ als, const float* __restrict__ ald,
                                              float* __restrict__ pei, int e) {
    int j = blockIdx.x * 256 + threadIdx.x;
    if (j >= e) return;
    int u = ssrc[j], d = sdst[j];
    float4 alu = *(const float4*)(als + 4 * (size_t)u);
    float4 asd = *(const float4*)(als + 4 * (size_t)d);
    float4 add4 = *(const float4*)(ald + 4 * (size_t)d);
    float4 m4 = lrelu4(make_float4(asd.x + add4.x, asd.y + add4.y, asd.z + add4.z, asd.w + add4.w));
    float4 e4 = lrelu4(make_float4(alu.x + add4.x, alu.y + add4.y, alu.z + add4.z, alu.w + add4.w));
    float4 pe;
    pe.x = __expf(e4.x - m4.x);
    pe.y = __expf(e4.y - m4.y);
    pe.z = __expf(e4.z - m4.z);
    pe.w = __expf(e4.w - m4.w);
    *(float4*)(pei + 4 * (size_t)j) = pe;
}

// One wave per destination node; lane = feature column (head = lane>>4).
// Chunk phase: lane=edge loads (u, pe4) coalesced -> LDS stash; z partial sums.
// Accumulate phase (round-3 proven shape): MLP-4 row-gather loop, one xh row
// per VMEM instruction, 4 independent loads in flight.
__global__ __launch_bounds__(256) void k_agg(const float* __restrict__ xh, const float* __restrict__ pei,
                                             const int* __restrict__ offs, const int* __restrict__ ssrc,
                                             const float* __restrict__ bias, float* __restrict__ hout,
                                             const float* __restrict__ outw, const float* __restrict__ outb,
                                             float* __restrict__ fout, int n) {
    __shared__ int s_u[4][64];
    __shared__ float s_pe[4][64 * 4];
    int wslot = threadIdx.x >> 6;
    int lane = threadIdx.x & 63;
    int v = (blockIdx.x * 256 + threadIdx.x) >> 6;
    if (v >= n) return;
    int head = lane >> 4;
    int* ub = s_u[wslot];
    float* peb = s_pe[wslot];

    int start = offs[v], end = offs[v + 1];
    float4 zp4 = make_float4(0.f, 0.f, 0.f, 0.f);
    float acc = xh[((size_t)v << 6) + lane];  // self term, pe_self = 1

    for (int s0 = start; s0 < end; s0 += 64) {
        int cnt = min(64, end - s0);
        bool act = lane < cnt;
        int u = 0;
        float4 pe = make_float4(0.f, 0.f, 0.f, 0.f);
        if (act) {
            u = ssrc[s0 + lane];
            pe = *(const float4*)(pei + 4 * (size_t)(s0 + lane));
        }
        zp4.x += pe.x; zp4.y += pe.y; zp4.z += pe.z; zp4.w += pe.w;
        if (act) {
            ub[lane] = u;
            *(float4*)(peb + lane * 4) = pe;  // same-wave LDS RAW, no barrier
        }
        int j = 0;
        for (; j + 4 <= cnt; j += 4) {
            int u0 = ub[j + 0], u1 = ub[j + 1], u2 = ub[j + 2], u3 = ub[j + 3];
            float p0 = peb[(j + 0) * 4 + head];
            float p1 = peb[(j + 1) * 4 + head];
            float p2 = peb[(j + 2) * 4 + head];
            float p3 = peb[(j + 3) * 4 + head];
            float x0 = xh[((size_t)u0 << 6) + lane];
            float x1 = xh[((size_t)u1 << 6) + lane];
            float x2 = xh[((size_t)u2 << 6) + lane];
            float x3 = xh[((size_t)u3 << 6) + lane];
            acc += p0 * x0;
            acc += p1 * x1;
            acc += p2 * x2;
            acc += p3 * x3;
        }
        for (; j < cnt; ++j) {
            int u0 = ub[j];
            float p0 = peb[j * 4 + head];
            acc += p0 * xh[((size_t)u0 << 6) + lane];
        }
    }
#pragma unroll
    for (int d = 1; d < 64; d <<= 1) {
        zp4.x += __shfl_xor(zp4.x, d, 64);
        zp4.y += __shfl_xor(zp4.y, d, 64);
        zp4.z += __shfl_xor(zp4.z, d, 64);
        zp4.w += __shfl_xor(zp4.w, d, 64);
    }
    float z = 1.f + pick4(zp4, head);  // +1 = self edge
    float o = acc / (z + 1e-16f) + bias[lane];
    o = fmaxf(o, 0.f);
    if (outw) {
        float tsum = o * outw[lane];
#pragma unroll
        for (int d = 32; d; d >>= 1) tsum += __shfl_down(tsum, d, 64);
        if (lane == 0) fout[v] = tsum + outb[0];
    } else {
        hout[((size_t)v << 6) + lane] = o;
    }
}

extern "C" void kernel_launch(void* const* d_in, const int* in_sizes, int n_in,
                              void* d_out, int out_size, void* d_ws, size_t ws_size,
                              hipStream_t stream) {
    const float* x = (const float*)d_in[0];
    const int* ei = (const int*)d_in[1];
    const float* w[3] = {(const float*)d_in[2], (const float*)d_in[6], (const float*)d_in[10]};
    const float* as[3] = {(const float*)d_in[3], (const float*)d_in[7], (const float*)d_in[11]};
    const float* ad[3] = {(const float*)d_in[4], (const float*)d_in[8], (const float*)d_in[12]};
    const float* b[3] = {(const float*)d_in[5], (const float*)d_in[9], (const float*)d_in[13]};
    const float* outw = (const float*)d_in[14];
    const float* outb = (const float*)d_in[15];

    const int N = in_sizes[0] / 128;
    const int E = in_sizes[1] / 2;
    const int* src = ei;
    const int* dst = ei + E;
    const int NB = (N + 255) / 256;  // 391 <= NBMAX

    char* ws = (char*)d_ws;
    auto alloc = [&](size_t bytes) -> void* {
        void* p = (void*)ws;
        ws += (bytes + 255) & ~(size_t)255;
        return p;
    };
    int* bhist = (int*)alloc(NBMAX * 4);
    int* boffs = (int*)alloc((NBMAX + 1) * 4);
    int* bfill = (int*)alloc(NBMAX * 4);
    int* offs = (int*)alloc((size_t)(N + 1) * 4);
    int* ssrc = (int*)alloc((size_t)E * 4);
    int* sdst = (int*)alloc((size_t)E * 4);
    float* pei = (float*)alloc((size_t)E * 4 * 4);
    float* xh = (float*)alloc((size_t)N * 64 * 4);
    float* hbuf = (float*)alloc((size_t)N * 64 * 4);
    float* als = (float*)alloc((size_t)N * 4 * 4);
    float* ald = (float*)alloc((size_t)N * 4 * 4);
    // edata (E*4B) aliases xh (N*256B): dead before the first k_gemm writes xh.
    unsigned int* edata = (unsigned int*)xh;

    k_zero<<<(NBMAX + 255) / 256, 256, 0, stream>>>(bhist, NBMAX);
    k_bhist<<<256, 256, 0, stream>>>(dst, bhist, E);
    k_bscan<<<1, 512, 0, stream>>>(bhist, boffs, bfill, NB, E);
    k_bscatter<<<(E + SCHUNK - 1) / SCHUNK, 512, 0, stream>>>(src, dst, boffs, bfill, edata, E);
    k_bfinal<<<NB, 256, 0, stream>>>(edata, boffs, offs, ssrc, sdst, N, NB);

    const int gblocks = (N + 63) / 64;
    const int ablocks = (N + 3) / 4;
    const int eblocks = (E + 255) / 256;

    k_gemm<128><<<gblocks, 256, 0, stream>>>(x, w[0], as[0], ad[0], xh, als, ald, N);
    k_edge<<<eblocks, 256, 0, stream>>>(ssrc, sdst, als, ald, pei, E);
    k_agg<<<ablocks, 256, 0, stream>>>(xh, pei, offs, ssrc, b[0], hbuf, nullptr, nullptr, nullptr, N);
    k_gemm<64><<<gblocks, 256, 0, stream>>>(hbuf, w[1], as[1], ad[1], xh, als, ald, N);
    k_edge<<<eblocks, 256, 0, stream>>>(ssrc, sdst, als, ald, pei, E);
    k_agg<<<ablocks, 256, 0, stream>>>(xh, pei, offs, ssrc, b[1], hbuf, nullptr, nullptr, nullptr, N);
    k_gemm<64><<<gblocks, 256, 0, stream>>>(hbuf, w[2], as[2], ad[2], xh, als, ald, N);
    k_edge<<<eblocks, 256, 0, stream>>>(ssrc, sdst, als, ald, pei, E);
    k_agg<<<ablocks, 256, 0, stream>>>(xh, pei, offs, ssrc, b[2], nullptr, outw, outb, (float*)d_out, N);
}

// Round 6
// 544.869 us; speedup vs baseline: 1.0400x; 1.0330x over previous
//
#include <hip/hip_runtime.h>

// GAT node regressor: 3 GAT layers (HID=64, 4 heads x 16) + linear head.
// CSR-by-dst built once per call via bucketed counting sort. Per layer:
//   k_gemm: xh = h@W (LDS-tiled fp32) fused with al_s/al_d head reductions
//   k_edge: per-edge softmax numerators pe[j][h] (coalesced, edge-parallel)
//   k_agg : wave-per-dst-node gather; 64-edge chunks staged in LDS with
//           head-transposed pe layout -> 2x ds_read_b128 per 4 edges (was 8x
//           b32); u stored as row byte-offset; z accumulated redundantly from
//           broadcast pe4 (no end shuffle-reduce). Layer 2 fuses h@out_w.

#define NBMAX 512   // max dst buckets (dst>>8); N=100K -> 391
#define SCHUNK 4096 // edges per k_bscatter block
#define BCAP 8192   // per-bucket LDS src capacity in k_bfinal (avg 4096)

__global__ __launch_bounds__(256) void k_zero(int* p, int n) {
    int i = blockIdx.x * 256 + threadIdx.x;
    if (i < n) p[i] = 0;
}

__global__ __launch_bounds__(256) void k_bhist(const int* __restrict__ dst, int* __restrict__ bhist, int e) {
    __shared__ unsigned int h[NBMAX];
    int t = threadIdx.x;
    h[t] = 0;
    h[t + 256] = 0;
    __syncthreads();
    for (int i = blockIdx.x * 256 + t; i < e; i += gridDim.x * 256)
        atomicAdd(&h[dst[i] >> 8], 1u);
    __syncthreads();
    if (h[t]) atomicAdd(&bhist[t], (int)h[t]);
    if (h[t + 256]) atomicAdd(&bhist[t + 256], (int)h[t + 256]);
}

__global__ __launch_bounds__(512) void k_bscan(const int* __restrict__ bhist, int* __restrict__ boffs,
                                               int* __restrict__ bfill, int nb, int e) {
    __shared__ int s[NBMAX];
    int t = threadIdx.x;
    int v = (t < nb) ? bhist[t] : 0;
    s[t] = v;
    __syncthreads();
    for (int o = 1; o < 512; o <<= 1) {
        int add = (t >= o) ? s[t - o] : 0;
        __syncthreads();
        s[t] += add;
        __syncthreads();
    }
    boffs[t] = s[t] - v;  // exclusive
    if (t == 511) boffs[512] = s[511];
    bfill[t] = 0;
}

// Block-local counting sort of a 4096-edge chunk by dst>>8, then streamed
// writes of sorted runs. Packs src (17b) | (dst&255)<<24 into 4B.
__global__ __launch_bounds__(512) void k_bscatter(const int* __restrict__ src, const int* __restrict__ dst,
                                                  const int* __restrict__ boffs, int* __restrict__ bfill,
                                                  unsigned int* __restrict__ edata, int e) {
    __shared__ unsigned int hist[NBMAX];   // counts, then cursor
    __shared__ unsigned int loc[NBMAX];    // local exclusive offsets
    __shared__ int gbase[NBMAX];
    __shared__ unsigned int stmp[NBMAX];
    __shared__ unsigned int sortbuf[SCHUNK];
    __shared__ int posbuf[SCHUNK];
    int t = threadIdx.x;
    int i0 = blockIdx.x * SCHUNK;
    int cnt = min(SCHUNK, e - i0);
    hist[t] = 0;
    __syncthreads();
    for (int j = t; j < cnt; j += 512) atomicAdd(&hist[dst[i0 + j] >> 8], 1u);
    __syncthreads();
    unsigned int v = hist[t];
    stmp[t] = v;
    __syncthreads();
    for (int o = 1; o < 512; o <<= 1) {
        unsigned int add = (t >= o) ? stmp[t - o] : 0;
        __syncthreads();
        stmp[t] += add;
        __syncthreads();
    }
    loc[t] = stmp[t] - v;
    int gb = 0;
    if (v > 0) gb = atomicAdd(&bfill[t], (int)v);  // reserve contiguous run in bucket t
    gbase[t] = boffs[t] + gb - (int)loc[t];
    hist[t] = loc[t];  // cursor
    __syncthreads();
    for (int j = t; j < cnt; j += 512) {
        int d = dst[i0 + j];
        int s = src[i0 + j];
        int b = d >> 8;
        unsigned int p = atomicAdd(&hist[b], 1u);
        sortbuf[p] = (unsigned int)s | ((unsigned int)(d & 255) << 24);
        posbuf[p] = gbase[b] + (int)p;
    }
    __syncthreads();
    for (int j = t; j < cnt; j += 512) edata[posbuf[j]] = sortbuf[j];
}

// One block per bucket: 256-bin counting sort by local dst; coalesced output
// of offs, ssrc (sorted srcs) and sdst (sorted dsts, for k_edge).
__global__ __launch_bounds__(256) void k_bfinal(const unsigned int* __restrict__ edata,
                                                const int* __restrict__ boffs, int* __restrict__ offs,
                                                int* __restrict__ ssrc, int* __restrict__ sdst,
                                                int n, int nb) {
    __shared__ unsigned int hist[256];
    __shared__ unsigned int stmp[256];
    __shared__ unsigned int loc[256];
    __shared__ unsigned int srcbuf[BCAP];
    __shared__ unsigned char dstbuf[BCAP];
    int b = blockIdx.x;
    int t = threadIdx.x;
    int e0 = boffs[b], e1 = boffs[b + 1];
    int cnt = e1 - e0;
    hist[t] = 0;
    __syncthreads();
    for (int j = t; j < cnt; j += 256) atomicAdd(&hist[edata[e0 + j] >> 24], 1u);
    __syncthreads();
    unsigned int v = hist[t];
    stmp[t] = v;
    __syncthreads();
    for (int o = 1; o < 256; o <<= 1) {
        unsigned int add = (t >= o) ? stmp[t - o] : 0;
        __syncthreads();
        stmp[t] += add;
        __syncthreads();
    }
    loc[t] = stmp[t] - v;
    int node = b * 256 + t;
    if (node < n) offs[node] = e0 + (int)loc[t];
    if (b == nb - 1 && t == 0) offs[n] = e1;
    hist[t] = loc[t];  // cursor
    __syncthreads();
    if (cnt <= BCAP) {
        for (int j = t; j < cnt; j += 256) {
            unsigned int p = edata[e0 + j];
            unsigned int pos = atomicAdd(&hist[p >> 24], 1u);
            srcbuf[pos] = p & 0xFFFFFFu;
            dstbuf[pos] = (unsigned char)(p >> 24);
        }
        __syncthreads();
        for (int j = t; j < cnt; j += 256) {
            ssrc[e0 + j] = (int)srcbuf[j];
            sdst[e0 + j] = b * 256 + (int)dstbuf[j];
        }
    } else {  // safety fallback (never hit for Poisson(4096) buckets)
        for (int j = t; j < cnt; j += 256) {
            unsigned int p = edata[e0 + j];
            unsigned int pos = atomicAdd(&hist[p >> 24], 1u);
            ssrc[e0 + (int)pos] = (int)(p & 0xFFFFFFu);
            sdst[e0 + (int)pos] = b * 256 + (int)(p >> 24);
        }
    }
}

// xh = h @ W  (h: [n, D_IN], W: [D_IN, 64]) fused with per-head attention logits.
template <int D_IN>
__global__ __launch_bounds__(256) void k_gemm(const float* __restrict__ h, const float* __restrict__ W,
                                              const float* __restrict__ asrc, const float* __restrict__ adst,
                                              float* __restrict__ xh, float* __restrict__ als,
                                              float* __restrict__ ald, int n) {
    constexpr int HSTR = D_IN + 4;
    __shared__ float hlds[64 * HSTR];
    int t = threadIdx.x;
    int node0 = blockIdx.x * 64;
    constexpr int HTOT = 64 * D_IN / 4;
    for (int i = t; i < HTOT; i += 256) {
        int f = i * 4;
        int nd = f / D_IN, k = f % D_IN;
        float4 val = make_float4(0.f, 0.f, 0.f, 0.f);
        if (node0 + nd < n) val = *(const float4*)(h + (size_t)(node0 + nd) * D_IN + k);
        *(float4*)(hlds + nd * HSTR + k) = val;
    }
    __syncthreads();
    int cg = t & 15, ng = t >> 4;
    float4 acc[4];
#pragma unroll
    for (int i = 0; i < 4; ++i) acc[i] = make_float4(0.f, 0.f, 0.f, 0.f);
    for (int k = 0; k < D_IN; k += 4) {
        float4 w0 = *(const float4*)(W + (size_t)(k + 0) * 64 + cg * 4);
        float4 w1 = *(const float4*)(W + (size_t)(k + 1) * 64 + cg * 4);
        float4 w2 = *(const float4*)(W + (size_t)(k + 2) * 64 + cg * 4);
        float4 w3 = *(const float4*)(W + (size_t)(k + 3) * 64 + cg * 4);
#pragma unroll
        for (int i = 0; i < 4; ++i) {
            float4 hv = *(const float4*)(hlds + (ng * 4 + i) * HSTR + k);
            acc[i].x += hv.x * w0.x + hv.y * w1.x + hv.z * w2.x + hv.w * w3.x;
            acc[i].y += hv.x * w0.y + hv.y * w1.y + hv.z * w2.y + hv.w * w3.y;
            acc[i].z += hv.x * w0.z + hv.y * w1.z + hv.z * w2.z + hv.w * w3.z;
            acc[i].w += hv.x * w0.w + hv.y * w1.w + hv.z * w2.w + hv.w * w3.w;
        }
    }
    float4 as4 = *(const float4*)(asrc + cg * 4);
    float4 ad4 = *(const float4*)(adst + cg * 4);
#pragma unroll
    for (int i = 0; i < 4; ++i) {
        int node = node0 + ng * 4 + i;
        float ps = acc[i].x * as4.x + acc[i].y * as4.y + acc[i].z * as4.z + acc[i].w * as4.w;
        float pd = acc[i].x * ad4.x + acc[i].y * ad4.y + acc[i].z * ad4.z + acc[i].w * ad4.w;
        ps += __shfl_xor(ps, 1, 64);
        ps += __shfl_xor(ps, 2, 64);
        pd += __shfl_xor(pd, 1, 64);
        pd += __shfl_xor(pd, 2, 64);
        if (node < n) {
            *(float4*)(xh + (size_t)node * 64 + cg * 4) = acc[i];
            if ((cg & 3) == 0) {
                als[node * 4 + (cg >> 2)] = ps;
                ald[node * 4 + (cg >> 2)] = pd;
            }
        }
    }
}

__device__ inline float4 lrelu4(float4 v) {
    float4 r;
    r.x = v.x >= 0.f ? v.x : 0.2f * v.x;
    r.y = v.y >= 0.f ? v.y : 0.2f * v.y;
    r.z = v.z >= 0.f ? v.z : 0.2f * v.z;
    r.w = v.w >= 0.f ? v.w : 0.2f * v.w;
    return r;
}

// Edge-parallel softmax numerators: pe[j][h] = exp(lrelu(als[u]+ald[d]) - m[d]),
// m[d] = lrelu(als[d]+ald[d]) (self-logit as per-head shift; single pass,
// algebraically identical to ref's max-subtraction).
__global__ __launch_bounds__(256) void k_edge(const int* __restrict__ ssrc, const int* __restrict__ sdst,
                                              const float* __restrict__ als, const float* __restrict__ ald,
                                              float* __restrict__ pei, int e) {
    int j = blockIdx.x * 256 + threadIdx.x;
    if (j >= e) return;
    int u = ssrc[j], d = sdst[j];
    float4 alu = *(const float4*)(als + 4 * (size_t)u);
    float4 asd = *(const float4*)(als + 4 * (size_t)d);
    float4 add4 = *(const float4*)(ald + 4 * (size_t)d);
    float4 m4 = lrelu4(make_float4(asd.x + add4.x, asd.y + add4.y, asd.z + add4.z, asd.w + add4.w));
    float4 e4 = lrelu4(make_float4(alu.x + add4.x, alu.y + add4.y, alu.z + add4.z, alu.w + add4.w));
    float4 pe;
    pe.x = __expf(e4.x - m4.x);
    pe.y = __expf(e4.y - m4.y);
    pe.z = __expf(e4.z - m4.z);
    pe.w = __expf(e4.w - m4.w);
    *(float4*)(pei + 4 * (size_t)j) = pe;
}

// One wave per destination node; lane = feature column (head = lane>>4).
// Chunk phase: lane=edge loads (u, pe4) coalesced; stash u as row BYTE offset
// and pe transposed [head][edge] in LDS (all 64 lanes write; pad u=v, pe=0).
// Accumulate: per 4 edges, 1 ds_read_b128 (u4, broadcast) + 1 ds_read_b128
// (pe4 of my head, broadcast) + 4 row gathers + 4 fmac; z accumulated
// redundantly per lane from the broadcast pe4 (no end shuffle-reduce).
__global__ __launch_bounds__(256) void k_agg(const float* __restrict__ xh, const float* __restrict__ pei,
                                             const int* __restrict__ offs, const int* __restrict__ ssrc,
                                             const float* __restrict__ bias, float* __restrict__ hout,
                                             const float* __restrict__ outw, const float* __restrict__ outb,
                                             float* __restrict__ fout, int n) {
    __shared__ int s_u[4][64];
    __shared__ float s_pe[4][4][64];  // [wslot][head][edge]
    int wslot = threadIdx.x >> 6;
    int lane = threadIdx.x & 63;
    int v = (blockIdx.x * 256 + threadIdx.x) >> 6;
    if (v >= n) return;
    int head = lane >> 4;
    int* ub = s_u[wslot];
    float* per = s_pe[wslot][head];      // read row for my head
    float* pew = &s_pe[wslot][0][lane];  // write base, stride 64 per head

    int start = offs[v], end = offs[v + 1];
    const char* xl = (const char*)(xh + lane);      // lane column folded into base
    float acc = *(const float*)(xl + ((size_t)(unsigned)v << 8));  // self, pe=1
    float zsum = 0.f;

    for (int s0 = start; s0 < end; s0 += 64) {
        int cnt = min(64, end - s0);
        bool act = lane < cnt;
        int u = v;
        float4 pe = make_float4(0.f, 0.f, 0.f, 0.f);
        if (act) {
            u = ssrc[s0 + lane];
            pe = *(const float4*)(pei + 4 * (size_t)(s0 + lane));
        }
        ub[lane] = u << 8;   // row byte offset; pad lanes point at v (pe=0)
        pew[0] = pe.x;       // transposed stash: bank stride 64 -> 2-way, free
        pew[64] = pe.y;
        pew[128] = pe.z;
        pew[192] = pe.w;
        // same-wave LDS RAW (in-order DS unit), no barrier needed
        int ng = (cnt + 3) >> 2;
        int g = 0;
        for (; g + 2 <= ng; g += 2) {
            int4 uu0 = *(const int4*)&ub[g * 4];
            int4 uu1 = *(const int4*)&ub[g * 4 + 4];
            float4 pp0 = *(const float4*)&per[g * 4];
            float4 pp1 = *(const float4*)&per[g * 4 + 4];
            float x0 = *(const float*)(xl + (size_t)(unsigned)uu0.x);
            float x1 = *(const float*)(xl + (size_t)(unsigned)uu0.y);
            float x2 = *(const float*)(xl + (size_t)(unsigned)uu0.z);
            float x3 = *(const float*)(xl + (size_t)(unsigned)uu0.w);
            float x4 = *(const float*)(xl + (size_t)(unsigned)uu1.x);
            float x5 = *(const float*)(xl + (size_t)(unsigned)uu1.y);
            float x6 = *(const float*)(xl + (size_t)(unsigned)uu1.z);
            float x7 = *(const float*)(xl + (size_t)(unsigned)uu1.w);
            zsum += pp0.x + pp0.y + pp0.z + pp0.w;
            zsum += pp1.x + pp1.y + pp1.z + pp1.w;
            acc += pp0.x * x0; acc += pp0.y * x1; acc += pp0.z * x2; acc += pp0.w * x3;
            acc += pp1.x * x4; acc += pp1.y * x5; acc += pp1.z * x6; acc += pp1.w * x7;
        }
        for (; g < ng; ++g) {
            int4 uu = *(const int4*)&ub[g * 4];
            float4 pp = *(const float4*)&per[g * 4];
            float x0 = *(const float*)(xl + (size_t)(unsigned)uu.x);
            float x1 = *(const float*)(xl + (size_t)(unsigned)uu.y);
            float x2 = *(const float*)(xl + (size_t)(unsigned)uu.z);
            float x3 = *(const float*)(xl + (size_t)(unsigned)uu.w);
            zsum += pp.x + pp.y + pp.z + pp.w;
            acc += pp.x * x0; acc += pp.y * x1; acc += pp.z * x2; acc += pp.w * x3;
        }
    }
    float z = 1.f + zsum;  // +1 = self edge
    float o = acc / (z + 1e-16f) + bias[lane];
    o = fmaxf(o, 0.f);
    if (outw) {
        float tsum = o * outw[lane];
#pragma unroll
        for (int d = 32; d; d >>= 1) tsum += __shfl_down(tsum, d, 64);
        if (lane == 0) fout[v] = tsum + outb[0];
    } else {
        hout[((size_t)v << 6) + lane] = o;
    }
}

extern "C" void kernel_launch(void* const* d_in, const int* in_sizes, int n_in,
                              void* d_out, int out_size, void* d_ws, size_t ws_size,
                              hipStream_t stream) {
    const float* x = (const float*)d_in[0];
    const int* ei = (const int*)d_in[1];
    const float* w[3] = {(const float*)d_in[2], (const float*)d_in[6], (const float*)d_in[10]};
    const float* as[3] = {(const float*)d_in[3], (const float*)d_in[7], (const float*)d_in[11]};
    const float* ad[3] = {(const float*)d_in[4], (const float*)d_in[8], (const float*)d_in[12]};
    const float* b[3] = {(const float*)d_in[5], (const float*)d_in[9], (const float*)d_in[13]};
    const float* outw = (const float*)d_in[14];
    const float* outb = (const float*)d_in[15];

    const int N = in_sizes[0] / 128;
    const int E = in_sizes[1] / 2;
    const int* src = ei;
    const int* dst = ei + E;
    const int NB = (N + 255) / 256;  // 391 <= NBMAX

    char* ws = (char*)d_ws;
    auto alloc = [&](size_t bytes) -> void* {
        void* p = (void*)ws;
        ws += (bytes + 255) & ~(size_t)255;
        return p;
    };
    int* bhist = (int*)alloc(NBMAX * 4);
    int* boffs = (int*)alloc((NBMAX + 1) * 4);
    int* bfill = (int*)alloc(NBMAX * 4);
    int* offs = (int*)alloc((size_t)(N + 1) * 4);
    int* ssrc = (int*)alloc((size_t)E * 4);
    int* sdst = (int*)alloc((size_t)E * 4);
    float* pei = (float*)alloc((size_t)E * 4 * 4);
    float* xh = (float*)alloc((size_t)N * 64 * 4);
    float* hbuf = (float*)alloc((size_t)N * 64 * 4);
    float* als = (float*)alloc((size_t)N * 4 * 4);
    float* ald = (float*)alloc((size_t)N * 4 * 4);
    // edata (E*4B) aliases xh (N*256B): dead before the first k_gemm writes xh.
    unsigned int* edata = (unsigned int*)xh;

    k_zero<<<(NBMAX + 255) / 256, 256, 0, stream>>>(bhist, NBMAX);
    k_bhist<<<256, 256, 0, stream>>>(dst, bhist, E);
    k_bscan<<<1, 512, 0, stream>>>(bhist, boffs, bfill, NB, E);
    k_bscatter<<<(E + SCHUNK - 1) / SCHUNK, 512, 0, stream>>>(src, dst, boffs, bfill, edata, E);
    k_bfinal<<<NB, 256, 0, stream>>>(edata, boffs, offs, ssrc, sdst, N, NB);

    const int gblocks = (N + 63) / 64;
    const int ablocks = (N + 3) / 4;
    const int eblocks = (E + 255) / 256;

    k_gemm<128><<<gblocks, 256, 0, stream>>>(x, w[0], as[0], ad[0], xh, als, ald, N);
    k_edge<<<eblocks, 256, 0, stream>>>(ssrc, sdst, als, ald, pei, E);
    k_agg<<<ablocks, 256, 0, stream>>>(xh, pei, offs, ssrc, b[0], hbuf, nullptr, nullptr, nullptr, N);
    k_gemm<64><<<gblocks, 256, 0, stream>>>(hbuf, w[1], as[1], ad[1], xh, als, ald, N);
    k_edge<<<eblocks, 256, 0, stream>>>(ssrc, sdst, als, ald, pei, E);
    k_agg<<<ablocks, 256, 0, stream>>>(xh, pei, offs, ssrc, b[1], hbuf, nullptr, nullptr, nullptr, N);
    k_gemm<64><<<gblocks, 256, 0, stream>>>(hbuf, w[2], as[2], ad[2], xh, als, ald, N);
    k_edge<<<eblocks, 256, 0, stream>>>(ssrc, sdst, als, ald, pei, E);
    k_agg<<<ablocks, 256, 0, stream>>>(xh, pei, offs, ssrc, b[2], nullptr, outw, outb, (float*)d_out, N);
}

// Round 7
// 464.015 us; speedup vs baseline: 1.2212x; 1.1742x over previous
//
#include <hip/hip_runtime.h>

// GAT node regressor: 3 GAT layers (HID=64, 4 heads x 16) + linear head.
// CSR-by-dst built once per call via bucketed counting sort. Per layer:
//   k_gemm: xh = h@W, W staged in LDS (compiler was fully unrolling the K-loop
//           and holding all W in 256 VGPRs -> 9% occupancy; LDS + unroll-cap
//           fixes it), fused with al_s/al_d head reductions
//   k_edge: per-edge softmax numerators pe[j][h] (coalesced, edge-parallel)
//   k_agg : wave-per-dst-node gather; 64-edge chunks staged in LDS with
//           head-transposed pe layout; u stored as row byte-offset; z
//           accumulated redundantly from broadcast pe4. Layer 2 fuses h@out_w.

#define NBMAX 512   // max dst buckets (dst>>8); N=100K -> 391
#define SCHUNK 4096 // edges per k_bscatter block
#define BCAP 8192   // per-bucket LDS src capacity in k_bfinal (avg 4096)

__global__ __launch_bounds__(256) void k_zero(int* p, int n) {
    int i = blockIdx.x * 256 + threadIdx.x;
    if (i < n) p[i] = 0;
}

__global__ __launch_bounds__(256) void k_bhist(const int* __restrict__ dst, int* __restrict__ bhist, int e) {
    __shared__ unsigned int h[NBMAX];
    int t = threadIdx.x;
    h[t] = 0;
    h[t + 256] = 0;
    __syncthreads();
    for (int i = blockIdx.x * 256 + t; i < e; i += gridDim.x * 256)
        atomicAdd(&h[dst[i] >> 8], 1u);
    __syncthreads();
    if (h[t]) atomicAdd(&bhist[t], (int)h[t]);
    if (h[t + 256]) atomicAdd(&bhist[t + 256], (int)h[t + 256]);
}

__global__ __launch_bounds__(512) void k_bscan(const int* __restrict__ bhist, int* __restrict__ boffs,
                                               int* __restrict__ bfill, int nb, int e) {
    __shared__ int s[NBMAX];
    int t = threadIdx.x;
    int v = (t < nb) ? bhist[t] : 0;
    s[t] = v;
    __syncthreads();
    for (int o = 1; o < 512; o <<= 1) {
        int add = (t >= o) ? s[t - o] : 0;
        __syncthreads();
        s[t] += add;
        __syncthreads();
    }
    boffs[t] = s[t] - v;  // exclusive
    if (t == 511) boffs[512] = s[511];
    bfill[t] = 0;
}

// Block-local counting sort of a 4096-edge chunk by dst>>8, then streamed
// writes of sorted runs. Packs src (17b) | (dst&255)<<24 into 4B.
__global__ __launch_bounds__(512) void k_bscatter(const int* __restrict__ src, const int* __restrict__ dst,
                                                  const int* __restrict__ boffs, int* __restrict__ bfill,
                                                  unsigned int* __restrict__ edata, int e) {
    __shared__ unsigned int hist[NBMAX];   // counts, then cursor
    __shared__ unsigned int loc[NBMAX];    // local exclusive offsets
    __shared__ int gbase[NBMAX];
    __shared__ unsigned int stmp[NBMAX];
    __shared__ unsigned int sortbuf[SCHUNK];
    __shared__ int posbuf[SCHUNK];
    int t = threadIdx.x;
    int i0 = blockIdx.x * SCHUNK;
    int cnt = min(SCHUNK, e - i0);
    hist[t] = 0;
    __syncthreads();
    for (int j = t; j < cnt; j += 512) atomicAdd(&hist[dst[i0 + j] >> 8], 1u);
    __syncthreads();
    unsigned int v = hist[t];
    stmp[t] = v;
    __syncthreads();
    for (int o = 1; o < 512; o <<= 1) {
        unsigned int add = (t >= o) ? stmp[t - o] : 0;
        __syncthreads();
        stmp[t] += add;
        __syncthreads();
    }
    loc[t] = stmp[t] - v;
    int gb = 0;
    if (v > 0) gb = atomicAdd(&bfill[t], (int)v);  // reserve contiguous run in bucket t
    gbase[t] = boffs[t] + gb - (int)loc[t];
    hist[t] = loc[t];  // cursor
    __syncthreads();
    for (int j = t; j < cnt; j += 512) {
        int d = dst[i0 + j];
        int s = src[i0 + j];
        int b = d >> 8;
        unsigned int p = atomicAdd(&hist[b], 1u);
        sortbuf[p] = (unsigned int)s | ((unsigned int)(d & 255) << 24);
        posbuf[p] = gbase[b] + (int)p;
    }
    __syncthreads();
    for (int j = t; j < cnt; j += 512) edata[posbuf[j]] = sortbuf[j];
}

// One block per bucket: 256-bin counting sort by local dst; coalesced output
// of offs, ssrc (sorted srcs) and sdst (sorted dsts, for k_edge).
__global__ __launch_bounds__(256) void k_bfinal(const unsigned int* __restrict__ edata,
                                                const int* __restrict__ boffs, int* __restrict__ offs,
                                                int* __restrict__ ssrc, int* __restrict__ sdst,
                                                int n, int nb) {
    __shared__ unsigned int hist[256];
    __shared__ unsigned int stmp[256];
    __shared__ unsigned int loc[256];
    __shared__ unsigned int srcbuf[BCAP];
    __shared__ unsigned char dstbuf[BCAP];
    int b = blockIdx.x;
    int t = threadIdx.x;
    int e0 = boffs[b], e1 = boffs[b + 1];
    int cnt = e1 - e0;
    hist[t] = 0;
    __syncthreads();
    for (int j = t; j < cnt; j += 256) atomicAdd(&hist[edata[e0 + j] >> 24], 1u);
    __syncthreads();
    unsigned int v = hist[t];
    stmp[t] = v;
    __syncthreads();
    for (int o = 1; o < 256; o <<= 1) {
        unsigned int add = (t >= o) ? stmp[t - o] : 0;
        __syncthreads();
        stmp[t] += add;
        __syncthreads();
    }
    loc[t] = stmp[t] - v;
    int node = b * 256 + t;
    if (node < n) offs[node] = e0 + (int)loc[t];
    if (b == nb - 1 && t == 0) offs[n] = e1;
    hist[t] = loc[t];  // cursor
    __syncthreads();
    if (cnt <= BCAP) {
        for (int j = t; j < cnt; j += 256) {
            unsigned int p = edata[e0 + j];
            unsigned int pos = atomicAdd(&hist[p >> 24], 1u);
            srcbuf[pos] = p & 0xFFFFFFu;
            dstbuf[pos] = (unsigned char)(p >> 24);
        }
        __syncthreads();
        for (int j = t; j < cnt; j += 256) {
            ssrc[e0 + j] = (int)srcbuf[j];
            sdst[e0 + j] = b * 256 + (int)dstbuf[j];
        }
    } else {  // safety fallback (never hit for Poisson(4096) buckets)
        for (int j = t; j < cnt; j += 256) {
            unsigned int p = edata[e0 + j];
            unsigned int pos = atomicAdd(&hist[p >> 24], 1u);
            ssrc[e0 + (int)pos] = (int)(p & 0xFFFFFFu);
            sdst[e0 + (int)pos] = b * 256 + (int)(p >> 24);
        }
    }
}

// xh = h @ W  (h: [n, D_IN], W: [D_IN, 64]) fused with per-head attention
// logits. W staged in LDS (reused by 64 nodes/block); K-loop unroll capped so
// the compiler doesn't hoist W into registers (was VGPR=256, 9% occupancy).
template <int D_IN>
__global__ __launch_bounds__(256) void k_gemm(const float* __restrict__ h, const float* __restrict__ W,
                                              const float* __restrict__ asrc, const float* __restrict__ adst,
                                              float* __restrict__ xh, float* __restrict__ als,
                                              float* __restrict__ ald, int n) {
    constexpr int HSTR = D_IN + 4;
    __shared__ float hlds[64 * HSTR];
    __shared__ float wlds[D_IN * 64];
    int t = threadIdx.x;
    int node0 = blockIdx.x * 64;
    // stage W (D_IN x 64) -- coalesced float4
    constexpr int WTOT = D_IN * 16;  // float4 count
    for (int i = t; i < WTOT; i += 256)
        *(float4*)(wlds + i * 4) = *(const float4*)(W + (size_t)i * 4);
    // stage h tile (64 x D_IN), padded stride
    constexpr int HTOT = 64 * D_IN / 4;
    for (int i = t; i < HTOT; i += 256) {
        int f = i * 4;
        int nd = f / D_IN, k = f % D_IN;
        float4 val = make_float4(0.f, 0.f, 0.f, 0.f);
        if (node0 + nd < n) val = *(const float4*)(h + (size_t)(node0 + nd) * D_IN + k);
        *(float4*)(hlds + nd * HSTR + k) = val;
    }
    __syncthreads();
    int cg = t & 15, ng = t >> 4;
    float4 acc[4];
#pragma unroll
    for (int i = 0; i < 4; ++i) acc[i] = make_float4(0.f, 0.f, 0.f, 0.f);
#pragma unroll 2
    for (int k = 0; k < D_IN; k += 4) {
        float4 w0 = *(const float4*)(wlds + (k + 0) * 64 + cg * 4);  // broadcast reads
        float4 w1 = *(const float4*)(wlds + (k + 1) * 64 + cg * 4);
        float4 w2 = *(const float4*)(wlds + (k + 2) * 64 + cg * 4);
        float4 w3 = *(const float4*)(wlds + (k + 3) * 64 + cg * 4);
#pragma unroll
        for (int i = 0; i < 4; ++i) {
            float4 hv = *(const float4*)(hlds + (ng * 4 + i) * HSTR + k);
            acc[i].x += hv.x * w0.x + hv.y * w1.x + hv.z * w2.x + hv.w * w3.x;
            acc[i].y += hv.x * w0.y + hv.y * w1.y + hv.z * w2.y + hv.w * w3.y;
            acc[i].z += hv.x * w0.z + hv.y * w1.z + hv.z * w2.z + hv.w * w3.z;
            acc[i].w += hv.x * w0.w + hv.y * w1.w + hv.z * w2.w + hv.w * w3.w;
        }
    }
    float4 as4 = *(const float4*)(asrc + cg * 4);
    float4 ad4 = *(const float4*)(adst + cg * 4);
#pragma unroll
    for (int i = 0; i < 4; ++i) {
        int node = node0 + ng * 4 + i;
        float ps = acc[i].x * as4.x + acc[i].y * as4.y + acc[i].z * as4.z + acc[i].w * as4.w;
        float pd = acc[i].x * ad4.x + acc[i].y * ad4.y + acc[i].z * ad4.z + acc[i].w * ad4.w;
        ps += __shfl_xor(ps, 1, 64);
        ps += __shfl_xor(ps, 2, 64);
        pd += __shfl_xor(pd, 1, 64);
        pd += __shfl_xor(pd, 2, 64);
        if (node < n) {
            *(float4*)(xh + (size_t)node * 64 + cg * 4) = acc[i];
            if ((cg & 3) == 0) {
                als[node * 4 + (cg >> 2)] = ps;
                ald[node * 4 + (cg >> 2)] = pd;
            }
        }
    }
}

__device__ inline float4 lrelu4(float4 v) {
    float4 r;
    r.x = v.x >= 0.f ? v.x : 0.2f * v.x;
    r.y = v.y >= 0.f ? v.y : 0.2f * v.y;
    r.z = v.z >= 0.f ? v.z : 0.2f * v.z;
    r.w = v.w >= 0.f ? v.w : 0.2f * v.w;
    return r;
}

// Edge-parallel softmax numerators: pe[j][h] = exp(lrelu(als[u]+ald[d]) - m[d]),
// m[d] = lrelu(als[d]+ald[d]) (self-logit as per-head shift; single pass,
// algebraically identical to ref's max-subtraction).
__global__ __launch_bounds__(256) void k_edge(const int* __restrict__ ssrc, const int* __restrict__ sdst,
                                              const float* __restrict__ als, const float* __restrict__ ald,
                                              float* __restrict__ pei, int e) {
    int j = blockIdx.x * 256 + threadIdx.x;
    if (j >= e) return;
    int u = ssrc[j], d = sdst[j];
    float4 alu = *(const float4*)(als + 4 * (size_t)u);
    float4 asd = *(const float4*)(als + 4 * (size_t)d);
    float4 add4 = *(const float4*)(ald + 4 * (size_t)d);
    float4 m4 = lrelu4(make_float4(asd.x + add4.x, asd.y + add4.y, asd.z + add4.z, asd.w + add4.w));
    float4 e4 = lrelu4(make_float4(alu.x + add4.x, alu.y + add4.y, alu.z + add4.z, alu.w + add4.w));
    float4 pe;
    pe.x = __expf(e4.x - m4.x);
    pe.y = __expf(e4.y - m4.y);
    pe.z = __expf(e4.z - m4.z);
    pe.w = __expf(e4.w - m4.w);
    *(float4*)(pei + 4 * (size_t)j) = pe;
}

// One wave per destination node; lane = feature column (head = lane>>4).
// Chunk phase: lane=edge loads (u, pe4) coalesced; stash u as row BYTE offset
// and pe transposed [head][edge] in LDS (all 64 lanes write; pad u=v, pe=0).
// Accumulate: per 4 edges, 2x ds_read_b128 (broadcast) + 4 row gathers + fmacs;
// z accumulated redundantly per lane (no end shuffle-reduce).
__global__ __launch_bounds__(256) void k_agg(const float* __restrict__ xh, const float* __restrict__ pei,
                                             const int* __restrict__ offs, const int* __restrict__ ssrc,
                                             const float* __restrict__ bias, float* __restrict__ hout,
                                             const float* __restrict__ outw, const float* __restrict__ outb,
                                             float* __restrict__ fout, int n) {
    __shared__ int s_u[4][64];
    __shared__ float s_pe[4][4][64];  // [wslot][head][edge]
    int wslot = threadIdx.x >> 6;
    int lane = threadIdx.x & 63;
    int v = (blockIdx.x * 256 + threadIdx.x) >> 6;
    if (v >= n) return;
    int head = lane >> 4;
    int* ub = s_u[wslot];
    float* per = s_pe[wslot][head];      // read row for my head
    float* pew = &s_pe[wslot][0][lane];  // write base, stride 64 per head

    int start = offs[v], end = offs[v + 1];
    const char* xl = (const char*)(xh + lane);      // lane column folded into base
    float acc = *(const float*)(xl + ((size_t)(unsigned)v << 8));  // self, pe=1
    float zsum = 0.f;

    for (int s0 = start; s0 < end; s0 += 64) {
        int cnt = min(64, end - s0);
        bool act = lane < cnt;
        int u = v;
        float4 pe = make_float4(0.f, 0.f, 0.f, 0.f);
        if (act) {
            u = ssrc[s0 + lane];
            pe = *(const float4*)(pei + 4 * (size_t)(s0 + lane));
        }
        ub[lane] = u << 8;   // row byte offset; pad lanes point at v (pe=0)
        pew[0] = pe.x;       // transposed stash: bank stride 64 -> 2-way, free
        pew[64] = pe.y;
        pew[128] = pe.z;
        pew[192] = pe.w;
        // same-wave LDS RAW (in-order DS unit), no barrier needed
        int ng = (cnt + 3) >> 2;
        int g = 0;
        for (; g + 2 <= ng; g += 2) {
            int4 uu0 = *(const int4*)&ub[g * 4];
            int4 uu1 = *(const int4*)&ub[g * 4 + 4];
            float4 pp0 = *(const float4*)&per[g * 4];
            float4 pp1 = *(const float4*)&per[g * 4 + 4];
            float x0 = *(const float*)(xl + (size_t)(unsigned)uu0.x);
            float x1 = *(const float*)(xl + (size_t)(unsigned)uu0.y);
            float x2 = *(const float*)(xl + (size_t)(unsigned)uu0.z);
            float x3 = *(const float*)(xl + (size_t)(unsigned)uu0.w);
            float x4 = *(const float*)(xl + (size_t)(unsigned)uu1.x);
            float x5 = *(const float*)(xl + (size_t)(unsigned)uu1.y);
            float x6 = *(const float*)(xl + (size_t)(unsigned)uu1.z);
            float x7 = *(const float*)(xl + (size_t)(unsigned)uu1.w);
            zsum += pp0.x + pp0.y + pp0.z + pp0.w;
            zsum += pp1.x + pp1.y + pp1.z + pp1.w;
            acc += pp0.x * x0; acc += pp0.y * x1; acc += pp0.z * x2; acc += pp0.w * x3;
            acc += pp1.x * x4; acc += pp1.y * x5; acc += pp1.z * x6; acc += pp1.w * x7;
        }
        for (; g < ng; ++g) {
            int4 uu = *(const int4*)&ub[g * 4];
            float4 pp = *(const float4*)&per[g * 4];
            float x0 = *(const float*)(xl + (size_t)(unsigned)uu.x);
            float x1 = *(const float*)(xl + (size_t)(unsigned)uu.y);
            float x2 = *(const float*)(xl + (size_t)(unsigned)uu.z);
            float x3 = *(const float*)(xl + (size_t)(unsigned)uu.w);
            zsum += pp.x + pp.y + pp.z + pp.w;
            acc += pp.x * x0; acc += pp.y * x1; acc += pp.z * x2; acc += pp.w * x3;
        }
    }
    float z = 1.f + zsum;  // +1 = self edge
    float o = acc / (z + 1e-16f) + bias[lane];
    o = fmaxf(o, 0.f);
    if (outw) {
        float tsum = o * outw[lane];
#pragma unroll
        for (int d = 32; d; d >>= 1) tsum += __shfl_down(tsum, d, 64);
        if (lane == 0) fout[v] = tsum + outb[0];
    } else {
        hout[((size_t)v << 6) + lane] = o;
    }
}

extern "C" void kernel_launch(void* const* d_in, const int* in_sizes, int n_in,
                              void* d_out, int out_size, void* d_ws, size_t ws_size,
                              hipStream_t stream) {
    const float* x = (const float*)d_in[0];
    const int* ei = (const int*)d_in[1];
    const float* w[3] = {(const float*)d_in[2], (const float*)d_in[6], (const float*)d_in[10]};
    const float* as[3] = {(const float*)d_in[3], (const float*)d_in[7], (const float*)d_in[11]};
    const float* ad[3] = {(const float*)d_in[4], (const float*)d_in[8], (const float*)d_in[12]};
    const float* b[3] = {(const float*)d_in[5], (const float*)d_in[9], (const float*)d_in[13]};
    const float* outw = (const float*)d_in[14];
    const float* outb = (const float*)d_in[15];

    const int N = in_sizes[0] / 128;
    const int E = in_sizes[1] / 2;
    const int* src = ei;
    const int* dst = ei + E;
    const int NB = (N + 255) / 256;  // 391 <= NBMAX

    char* ws = (char*)d_ws;
    auto alloc = [&](size_t bytes) -> void* {
        void* p = (void*)ws;
        ws += (bytes + 255) & ~(size_t)255;
        return p;
    };
    int* bhist = (int*)alloc(NBMAX * 4);
    int* boffs = (int*)alloc((NBMAX + 1) * 4);
    int* bfill = (int*)alloc(NBMAX * 4);
    int* offs = (int*)alloc((size_t)(N + 1) * 4);
    int* ssrc = (int*)alloc((size_t)E * 4);
    int* sdst = (int*)alloc((size_t)E * 4);
    float* pei = (float*)alloc((size_t)E * 4 * 4);
    float* xh = (float*)alloc((size_t)N * 64 * 4);
    float* hbuf = (float*)alloc((size_t)N * 64 * 4);
    float* als = (float*)alloc((size_t)N * 4 * 4);
    float* ald = (float*)alloc((size_t)N * 4 * 4);
    // edata (E*4B) aliases xh (N*256B): dead before the first k_gemm writes xh.
    unsigned int* edata = (unsigned int*)xh;

    k_zero<<<(NBMAX + 255) / 256, 256, 0, stream>>>(bhist, NBMAX);
    k_bhist<<<256, 256, 0, stream>>>(dst, bhist, E);
    k_bscan<<<1, 512, 0, stream>>>(bhist, boffs, bfill, NB, E);
    k_bscatter<<<(E + SCHUNK - 1) / SCHUNK, 512, 0, stream>>>(src, dst, boffs, bfill, edata, E);
    k_bfinal<<<NB, 256, 0, stream>>>(edata, boffs, offs, ssrc, sdst, N, NB);

    const int gblocks = (N + 63) / 64;
    const int ablocks = (N + 3) / 4;
    const int eblocks = (E + 255) / 256;

    k_gemm<128><<<gblocks, 256, 0, stream>>>(x, w[0], as[0], ad[0], xh, als, ald, N);
    k_edge<<<eblocks, 256, 0, stream>>>(ssrc, sdst, als, ald, pei, E);
    k_agg<<<ablocks, 256, 0, stream>>>(xh, pei, offs, ssrc, b[0], hbuf, nullptr, nullptr, nullptr, N);
    k_gemm<64><<<gblocks, 256, 0, stream>>>(hbuf, w[1], as[1], ad[1], xh, als, ald, N);
    k_edge<<<eblocks, 256, 0, stream>>>(ssrc, sdst, als, ald, pei, E);
    k_agg<<<ablocks, 256, 0, stream>>>(xh, pei, offs, ssrc, b[1], hbuf, nullptr, nullptr, nullptr, N);
    k_gemm<64><<<gblocks, 256, 0, stream>>>(hbuf, w[2], as[2], ad[2], xh, als, ald, N);
    k_edge<<<eblocks, 256, 0, stream>>>(ssrc, sdst, als, ald, pei, E);
    k_agg<<<ablocks, 256, 0, stream>>>(xh, pei, offs, ssrc, b[2], nullptr, outw, outb, (float*)d_out, N);
}

// Round 8
// 460.617 us; speedup vs baseline: 1.2302x; 1.0074x over previous
//
#include <hip/hip_runtime.h>

// GAT node regressor: 3 GAT layers (HID=64, 4 heads x 16) + linear head.
// CSR-by-dst built once per call via bucketed counting sort. Per layer:
//   k_gemm: xh = h@W, h-tile + W staged in LDS (unroll-capped so W is not
//           register-hoisted), fused al_s/al_d head reductions.
//   k_agg : wave-per-dst-node gather; chunk phase computes per-edge softmax
//           numerators inline (lane=edge, all 4 heads) into a head-transposed
//           LDS stash; accumulate phase reads broadcast b128 pairs + 4 row
//           gathers per group, dual fmac chains. Layer 2 fuses h@out_w.

#define NBMAX 512   // max dst buckets (dst>>8); N=100K -> 391
#define SCHUNK 4096 // edges per k_bscatter block
#define BCAP 8192   // per-bucket LDS src capacity in k_bfinal (avg 4096)

__global__ __launch_bounds__(256) void k_zero(int* p, int n) {
    int i = blockIdx.x * 256 + threadIdx.x;
    if (i < n) p[i] = 0;
}

__global__ __launch_bounds__(256) void k_bhist(const int* __restrict__ dst, int* __restrict__ bhist, int e) {
    __shared__ unsigned int h[NBMAX];
    int t = threadIdx.x;
    h[t] = 0;
    h[t + 256] = 0;
    __syncthreads();
    for (int i = blockIdx.x * 256 + t; i < e; i += gridDim.x * 256)
        atomicAdd(&h[dst[i] >> 8], 1u);
    __syncthreads();
    if (h[t]) atomicAdd(&bhist[t], (int)h[t]);
    if (h[t + 256]) atomicAdd(&bhist[t + 256], (int)h[t + 256]);
}

__global__ __launch_bounds__(512) void k_bscan(const int* __restrict__ bhist, int* __restrict__ boffs,
                                               int* __restrict__ bfill, int nb, int e) {
    __shared__ int s[NBMAX];
    int t = threadIdx.x;
    int v = (t < nb) ? bhist[t] : 0;
    s[t] = v;
    __syncthreads();
    for (int o = 1; o < 512; o <<= 1) {
        int add = (t >= o) ? s[t - o] : 0;
        __syncthreads();
        s[t] += add;
        __syncthreads();
    }
    boffs[t] = s[t] - v;  // exclusive
    if (t == 511) boffs[512] = s[511];
    bfill[t] = 0;
}

// Block-local counting sort of a 4096-edge chunk by dst>>8, then streamed
// writes of sorted runs. Packs src (17b) | (dst&255)<<24 into 4B.
__global__ __launch_bounds__(512) void k_bscatter(const int* __restrict__ src, const int* __restrict__ dst,
                                                  const int* __restrict__ boffs, int* __restrict__ bfill,
                                                  unsigned int* __restrict__ edata, int e) {
    __shared__ unsigned int hist[NBMAX];   // counts, then cursor
    __shared__ unsigned int loc[NBMAX];    // local exclusive offsets
    __shared__ int gbase[NBMAX];
    __shared__ unsigned int stmp[NBMAX];
    __shared__ unsigned int sortbuf[SCHUNK];
    __shared__ int posbuf[SCHUNK];
    int t = threadIdx.x;
    int i0 = blockIdx.x * SCHUNK;
    int cnt = min(SCHUNK, e - i0);
    hist[t] = 0;
    __syncthreads();
    for (int j = t; j < cnt; j += 512) atomicAdd(&hist[dst[i0 + j] >> 8], 1u);
    __syncthreads();
    unsigned int v = hist[t];
    stmp[t] = v;
    __syncthreads();
    for (int o = 1; o < 512; o <<= 1) {
        unsigned int add = (t >= o) ? stmp[t - o] : 0;
        __syncthreads();
        stmp[t] += add;
        __syncthreads();
    }
    loc[t] = stmp[t] - v;
    int gb = 0;
    if (v > 0) gb = atomicAdd(&bfill[t], (int)v);  // reserve contiguous run in bucket t
    gbase[t] = boffs[t] + gb - (int)loc[t];
    hist[t] = loc[t];  // cursor
    __syncthreads();
    for (int j = t; j < cnt; j += 512) {
        int d = dst[i0 + j];
        int s = src[i0 + j];
        int b = d >> 8;
        unsigned int p = atomicAdd(&hist[b], 1u);
        sortbuf[p] = (unsigned int)s | ((unsigned int)(d & 255) << 24);
        posbuf[p] = gbase[b] + (int)p;
    }
    __syncthreads();
    for (int j = t; j < cnt; j += 512) edata[posbuf[j]] = sortbuf[j];
}

// One block per bucket: 256-bin counting sort by local dst; coalesced offs
// and ssrc output (sdst no longer needed — logits fused into k_agg).
__global__ __launch_bounds__(256) void k_bfinal(const unsigned int* __restrict__ edata,
                                                const int* __restrict__ boffs, int* __restrict__ offs,
                                                int* __restrict__ ssrc, int n, int nb) {
    __shared__ unsigned int hist[256];
    __shared__ unsigned int stmp[256];
    __shared__ unsigned int loc[256];
    __shared__ unsigned int srcbuf[BCAP];
    int b = blockIdx.x;
    int t = threadIdx.x;
    int e0 = boffs[b], e1 = boffs[b + 1];
    int cnt = e1 - e0;
    hist[t] = 0;
    __syncthreads();
    for (int j = t; j < cnt; j += 256) atomicAdd(&hist[edata[e0 + j] >> 24], 1u);
    __syncthreads();
    unsigned int v = hist[t];
    stmp[t] = v;
    __syncthreads();
    for (int o = 1; o < 256; o <<= 1) {
        unsigned int add = (t >= o) ? stmp[t - o] : 0;
        __syncthreads();
        stmp[t] += add;
        __syncthreads();
    }
    loc[t] = stmp[t] - v;
    int node = b * 256 + t;
    if (node < n) offs[node] = e0 + (int)loc[t];
    if (b == nb - 1 && t == 0) offs[n] = e1;
    hist[t] = loc[t];  // cursor
    __syncthreads();
    if (cnt <= BCAP) {
        for (int j = t; j < cnt; j += 256) {
            unsigned int p = edata[e0 + j];
            unsigned int pos = atomicAdd(&hist[p >> 24], 1u);
            srcbuf[pos] = p & 0xFFFFFFu;
        }
        __syncthreads();
        for (int j = t; j < cnt; j += 256) ssrc[e0 + j] = (int)srcbuf[j];
    } else {  // safety fallback (never hit for Poisson(4096) buckets)
        for (int j = t; j < cnt; j += 256) {
            unsigned int p = edata[e0 + j];
            unsigned int pos = atomicAdd(&hist[p >> 24], 1u);
            ssrc[e0 + (int)pos] = (int)(p & 0xFFFFFFu);
        }
    }
}

// xh = h @ W  (h: [n, D_IN], W: [D_IN, 64]) fused with per-head attention
// logits. ROWS-node tile; thread (cg,ng) computes ROWS/16 nodes x 4 cols.
// W staged in LDS; unroll capped so W isn't register-hoisted (VGPR=256 trap).
// ROWS=32 for D_IN=128 keeps LDS < 50KB -> 3 blocks/CU.
template <int D_IN, int ROWS>
__global__ __launch_bounds__(256) void k_gemm(const float* __restrict__ h, const float* __restrict__ W,
                                              const float* __restrict__ asrc, const float* __restrict__ adst,
                                              float* __restrict__ xh, float* __restrict__ als,
                                              float* __restrict__ ald, int n) {
    constexpr int HSTR = D_IN + 4;
    constexpr int NPT = ROWS / 16;  // nodes per thread
    __shared__ float hlds[ROWS * HSTR];
    __shared__ float wlds[D_IN * 64];
    int t = threadIdx.x;
    int node0 = blockIdx.x * ROWS;
    constexpr int WTOT = D_IN * 16;  // float4 count
    for (int i = t; i < WTOT; i += 256)
        *(float4*)(wlds + i * 4) = *(const float4*)(W + (size_t)i * 4);
    constexpr int HTOT = ROWS * D_IN / 4;
    for (int i = t; i < HTOT; i += 256) {
        int f = i * 4;
        int nd = f / D_IN, k = f % D_IN;
        float4 val = make_float4(0.f, 0.f, 0.f, 0.f);
        if (node0 + nd < n) val = *(const float4*)(h + (size_t)(node0 + nd) * D_IN + k);
        *(float4*)(hlds + nd * HSTR + k) = val;
    }
    __syncthreads();
    int cg = t & 15, ng = t >> 4;
    float4 acc[NPT];
#pragma unroll
    for (int i = 0; i < NPT; ++i) acc[i] = make_float4(0.f, 0.f, 0.f, 0.f);
#pragma unroll 2
    for (int k = 0; k < D_IN; k += 4) {
        float4 w0 = *(const float4*)(wlds + (k + 0) * 64 + cg * 4);  // broadcast reads
        float4 w1 = *(const float4*)(wlds + (k + 1) * 64 + cg * 4);
        float4 w2 = *(const float4*)(wlds + (k + 2) * 64 + cg * 4);
        float4 w3 = *(const float4*)(wlds + (k + 3) * 64 + cg * 4);
#pragma unroll
        for (int i = 0; i < NPT; ++i) {
            float4 hv = *(const float4*)(hlds + (ng * NPT + i) * HSTR + k);
            acc[i].x += hv.x * w0.x + hv.y * w1.x + hv.z * w2.x + hv.w * w3.x;
            acc[i].y += hv.x * w0.y + hv.y * w1.y + hv.z * w2.y + hv.w * w3.y;
            acc[i].z += hv.x * w0.z + hv.y * w1.z + hv.z * w2.z + hv.w * w3.z;
            acc[i].w += hv.x * w0.w + hv.y * w1.w + hv.z * w2.w + hv.w * w3.w;
        }
    }
    float4 as4 = *(const float4*)(asrc + cg * 4);
    float4 ad4 = *(const float4*)(adst + cg * 4);
#pragma unroll
    for (int i = 0; i < NPT; ++i) {
        int node = node0 + ng * NPT + i;
        float ps = acc[i].x * as4.x + acc[i].y * as4.y + acc[i].z * as4.z + acc[i].w * as4.w;
        float pd = acc[i].x * ad4.x + acc[i].y * ad4.y + acc[i].z * ad4.z + acc[i].w * ad4.w;
        ps += __shfl_xor(ps, 1, 64);
        ps += __shfl_xor(ps, 2, 64);
        pd += __shfl_xor(pd, 1, 64);
        pd += __shfl_xor(pd, 2, 64);
        if (node < n) {
            *(float4*)(xh + (size_t)node * 64 + cg * 4) = acc[i];
            if ((cg & 3) == 0) {
                als[node * 4 + (cg >> 2)] = ps;
                ald[node * 4 + (cg >> 2)] = pd;
            }
        }
    }
}

__device__ inline float4 lrelu4(float4 v) {
    float4 r;
    r.x = v.x >= 0.f ? v.x : 0.2f * v.x;
    r.y = v.y >= 0.f ? v.y : 0.2f * v.y;
    r.z = v.z >= 0.f ? v.z : 0.2f * v.z;
    r.w = v.w >= 0.f ? v.w : 0.2f * v.w;
    return r;
}

// One wave per destination node; lane = feature column (head = lane>>4).
// Chunk phase (lane=edge): gather als[u] (L2-resident, 1.6MB), compute all 4
// heads' pe = exp(lrelu(als[u]+ald[v]) - m_v) inline, stash u as row BYTE
// offset + pe transposed [head][edge] in LDS (all 64 lanes write; pad u=v,
// pe=0). m_v = self-logit per head (single pass, algebraically identical to
// ref's max-subtraction). Accumulate: per 4 edges, 2x broadcast ds_read_b128
// + 4 row gathers; dual fmac chains; z redundant per lane. Layer 2 fuses
// h@out_w via shuffle.
__global__ __launch_bounds__(256) void k_agg(const float* __restrict__ xh, const float* __restrict__ als,
                                             const float* __restrict__ ald, const int* __restrict__ offs,
                                             const int* __restrict__ ssrc, const float* __restrict__ bias,
                                             float* __restrict__ hout, const float* __restrict__ outw,
                                             const float* __restrict__ outb, float* __restrict__ fout, int n) {
    __shared__ int s_u[4][64];
    __shared__ float s_pe[4][4][64];  // [wslot][head][edge]
    int wslot = threadIdx.x >> 6;
    int lane = threadIdx.x & 63;
    int v = (blockIdx.x * 256 + threadIdx.x) >> 6;
    if (v >= n) return;
    int head = lane >> 4;
    int* ub = s_u[wslot];
    float* per = s_pe[wslot][head];      // read row for my head
    float* pew = &s_pe[wslot][0][lane];  // write base, stride 64 per head

    int start = offs[v], end = offs[v + 1];
    float4 ald4 = *(const float4*)(ald + 4 * (size_t)v);
    float4 als4v = *(const float4*)(als + 4 * (size_t)v);
    float4 m4 = lrelu4(make_float4(als4v.x + ald4.x, als4v.y + ald4.y, als4v.z + ald4.z, als4v.w + ald4.w));

    const char* xl = (const char*)(xh + lane);      // lane column folded into base
    float acc0 = *(const float*)(xl + ((size_t)(unsigned)v << 8));  // self, pe=1
    float acc1 = 0.f;
    float zs0 = 0.f, zs1 = 0.f;

    for (int s0 = start; s0 < end; s0 += 64) {
        int cnt = min(64, end - s0);
        bool act = lane < cnt;
        int u = v;
        float4 alu = make_float4(-1e30f, -1e30f, -1e30f, -1e30f);
        if (act) {
            u = ssrc[s0 + lane];
            alu = *(const float4*)(als + 4 * (size_t)u);
        }
        float4 e4 = lrelu4(make_float4(alu.x + ald4.x, alu.y + ald4.y, alu.z + ald4.z, alu.w + ald4.w));
        float4 pe;
        pe.x = __expf(e4.x - m4.x);  // inactive lanes -> exp(-huge) = 0
        pe.y = __expf(e4.y - m4.y);
        pe.z = __expf(e4.z - m4.z);
        pe.w = __expf(e4.w - m4.w);
        ub[lane] = u << 8;   // row byte offset; pad lanes point at v (pe=0)
        pew[0] = pe.x;       // transposed stash: bank stride 64 -> 2-way, free
        pew[64] = pe.y;
        pew[128] = pe.z;
        pew[192] = pe.w;
        // same-wave LDS RAW (in-order DS unit), no barrier needed
        int ngp = (cnt + 3) >> 2;
        int g = 0;
        for (; g + 2 <= ngp; g += 2) {
            int4 uu0 = *(const int4*)&ub[g * 4];
            int4 uu1 = *(const int4*)&ub[g * 4 + 4];
            float4 pp0 = *(const float4*)&per[g * 4];
            float4 pp1 = *(const float4*)&per[g * 4 + 4];
            float x0 = *(const float*)(xl + (size_t)(unsigned)uu0.x);
            float x1 = *(const float*)(xl + (size_t)(unsigned)uu0.y);
            float x2 = *(const float*)(xl + (size_t)(unsigned)uu0.z);
            float x3 = *(const float*)(xl + (size_t)(unsigned)uu0.w);
            float x4 = *(const float*)(xl + (size_t)(unsigned)uu1.x);
            float x5 = *(const float*)(xl + (size_t)(unsigned)uu1.y);
            float x6 = *(const float*)(xl + (size_t)(unsigned)uu1.z);
            float x7 = *(const float*)(xl + (size_t)(unsigned)uu1.w);
            zs0 += (pp0.x + pp0.y) + (pp0.z + pp0.w);
            zs1 += (pp1.x + pp1.y) + (pp1.z + pp1.w);
            acc0 += pp0.x * x0; acc0 += pp0.y * x1; acc0 += pp0.z * x2; acc0 += pp0.w * x3;
            acc1 += pp1.x * x4; acc1 += pp1.y * x5; acc1 += pp1.z * x6; acc1 += pp1.w * x7;
        }
        for (; g < ngp; ++g) {
            int4 uu = *(const int4*)&ub[g * 4];
            float4 pp = *(const float4*)&per[g * 4];
            float x0 = *(const float*)(xl + (size_t)(unsigned)uu.x);
            float x1 = *(const float*)(xl + (size_t)(unsigned)uu.y);
            float x2 = *(const float*)(xl + (size_t)(unsigned)uu.z);
            float x3 = *(const float*)(xl + (size_t)(unsigned)uu.w);
            zs0 += (pp.x + pp.y) + (pp.z + pp.w);
            acc0 += pp.x * x0; acc0 += pp.y * x1; acc0 += pp.z * x2; acc0 += pp.w * x3;
        }
    }
    float z = 1.f + zs0 + zs1;  // +1 = self edge
    float o = (acc0 + acc1) / (z + 1e-16f) + bias[lane];
    o = fmaxf(o, 0.f);
    if (outw) {
        float tsum = o * outw[lane];
#pragma unroll
        for (int d = 32; d; d >>= 1) tsum += __shfl_down(tsum, d, 64);
        if (lane == 0) fout[v] = tsum + outb[0];
    } else {
        hout[((size_t)v << 6) + lane] = o;
    }
}

extern "C" void kernel_launch(void* const* d_in, const int* in_sizes, int n_in,
                              void* d_out, int out_size, void* d_ws, size_t ws_size,
                              hipStream_t stream) {
    const float* x = (const float*)d_in[0];
    const int* ei = (const int*)d_in[1];
    const float* w[3] = {(const float*)d_in[2], (const float*)d_in[6], (const float*)d_in[10]};
    const float* as[3] = {(const float*)d_in[3], (const float*)d_in[7], (const float*)d_in[11]};
    const float* ad[3] = {(const float*)d_in[4], (const float*)d_in[8], (const float*)d_in[12]};
    const float* b[3] = {(const float*)d_in[5], (const float*)d_in[9], (const float*)d_in[13]};
    const float* outw = (const float*)d_in[14];
    const float* outb = (const float*)d_in[15];

    const int N = in_sizes[0] / 128;
    const int E = in_sizes[1] / 2;
    const int* src = ei;
    const int* dst = ei + E;
    const int NB = (N + 255) / 256;  // 391 <= NBMAX

    char* ws = (char*)d_ws;
    auto alloc = [&](size_t bytes) -> void* {
        void* p = (void*)ws;
        ws += (bytes + 255) & ~(size_t)255;
        return p;
    };
    int* bhist = (int*)alloc(NBMAX * 4);
    int* boffs = (int*)alloc((NBMAX + 1) * 4);
    int* bfill = (int*)alloc(NBMAX * 4);
    int* offs = (int*)alloc((size_t)(N + 1) * 4);
    int* ssrc = (int*)alloc((size_t)E * 4);
    float* xh = (float*)alloc((size_t)N * 64 * 4);
    float* hbuf = (float*)alloc((size_t)N * 64 * 4);
    float* als = (float*)alloc((size_t)N * 4 * 4);
    float* ald = (float*)alloc((size_t)N * 4 * 4);
    // edata (E*4B) aliases xh (N*256B): dead before the first k_gemm writes xh.
    unsigned int* edata = (unsigned int*)xh;

    k_zero<<<(NBMAX + 255) / 256, 256, 0, stream>>>(bhist, NBMAX);
    k_bhist<<<256, 256, 0, stream>>>(dst, bhist, E);
    k_bscan<<<1, 512, 0, stream>>>(bhist, boffs, bfill, NB, E);
    k_bscatter<<<(E + SCHUNK - 1) / SCHUNK, 512, 0, stream>>>(src, dst, boffs, bfill, edata, E);
    k_bfinal<<<NB, 256, 0, stream>>>(edata, boffs, offs, ssrc, N, NB);

    const int g128 = (N + 31) / 32;
    const int g64 = (N + 63) / 64;
    const int ablocks = (N + 3) / 4;

    k_gemm<128, 32><<<g128, 256, 0, stream>>>(x, w[0], as[0], ad[0], xh, als, ald, N);
    k_agg<<<ablocks, 256, 0, stream>>>(xh, als, ald, offs, ssrc, b[0], hbuf, nullptr, nullptr, nullptr, N);
    k_gemm<64, 64><<<g64, 256, 0, stream>>>(hbuf, w[1], as[1], ad[1], xh, als, ald, N);
    k_agg<<<ablocks, 256, 0, stream>>>(xh, als, ald, offs, ssrc, b[1], hbuf, nullptr, nullptr, nullptr, N);
    k_gemm<64, 64><<<g64, 256, 0, stream>>>(hbuf, w[2], as[2], ad[2], xh, als, ald, N);
    k_agg<<<ablocks, 256, 0, stream>>>(xh, als, ald, offs, ssrc, b[2], nullptr, outw, outb, (float*)d_out, N);
}